// Round 1
// baseline (1291.134 us; speedup 1.0000x reference)
//
#include <hip/hip_runtime.h>
#include <hip/hip_bf16.h>
#include <cstdio>
#include <cstdint>

#define B_SZ    2
#define L_SEQ   1024
#define DMODEL  768
#define DINNER  1536
#define DSTATE  16
#define DTRANK  48
#define VOCAB   32000
#define BL      (B_SZ * L_SEQ)   // 2048

typedef __bf16 bf16;
typedef __bf16 bf16x8 __attribute__((ext_vector_type(8)));
typedef __bf16 bf16x4 __attribute__((ext_vector_type(4)));
typedef float  f32x4  __attribute__((ext_vector_type(4)));

// ---------------- async global->LDS (16B/lane, wave-uniform base + lane*16) --
__device__ __forceinline__ void gload16(const void* g, void* l) {
  __builtin_amdgcn_global_load_lds(
      (const __attribute__((address_space(1))) void*)g,
      (__attribute__((address_space(3))) void*)l, 16, 0, 0);
}

// ---------------- embedding gather ------------------------------------------
__global__ void k_embed(const int* __restrict__ ids, const float* __restrict__ emb,
                        float* __restrict__ xw) {
  const int row = blockIdx.x;
  const int id  = ids[row];
  const float4* s = (const float4*)(emb + (size_t)id * DMODEL);
  float4* d = (float4*)(xw + (size_t)row * DMODEL);
  for (int i = threadIdx.x; i < DMODEL / 4; i += blockDim.x) d[i] = s[i];
}

// ---------------- f32 -> bf16 hi/lo split (activations) ---------------------
__global__ void k_split4(const float* __restrict__ x, bf16* __restrict__ h,
                         bf16* __restrict__ l, int n4) {
  const int i = blockIdx.x * blockDim.x + threadIdx.x;
  if (i >= n4) return;
  const float4 v = ((const float4*)x)[i];
  bf16x4 hv, lv;
  hv[0] = (bf16)v.x; hv[1] = (bf16)v.y; hv[2] = (bf16)v.z; hv[3] = (bf16)v.w;
  lv[0] = (bf16)(v.x - (float)hv[0]); lv[1] = (bf16)(v.y - (float)hv[1]);
  lv[2] = (bf16)(v.z - (float)hv[2]); lv[3] = (bf16)(v.w - (float)hv[3]);
  *(bf16x4*)(h + (size_t)i * 4) = hv;
  *(bf16x4*)(l + (size_t)i * 4) = lv;
}

__global__ void k_cvt4(const float* __restrict__ x, bf16* __restrict__ h, int n4) {
  const int i = blockIdx.x * blockDim.x + threadIdx.x;
  if (i >= n4) return;
  const float4 v = ((const float4*)x)[i];
  bf16x4 hv;
  hv[0] = (bf16)v.x; hv[1] = (bf16)v.y; hv[2] = (bf16)v.z; hv[3] = (bf16)v.w;
  *(bf16x4*)(h + (size_t)i * 4) = hv;
}

// ---------------- weight transpose + convert: W(K,N) f32 -> WT(N,K) bf16 ----
template<bool SPLIT>
__global__ void k_tconv(const float* __restrict__ W, bf16* __restrict__ Th,
                        bf16* __restrict__ Tl, int K, int N) {
  __shared__ float t[32][33];
  const int n0 = blockIdx.x * 32;
  const int k0 = blockIdx.y * 32;
  const int tx = threadIdx.x;   // 0..31
  const int ty = threadIdx.y;   // 0..7
#pragma unroll
  for (int i = 0; i < 4; i++)
    t[ty + i * 8][tx] = W[(size_t)(k0 + ty + i * 8) * N + n0 + tx];
  __syncthreads();
#pragma unroll
  for (int i = 0; i < 4; i++) {
    const float v = t[tx][ty + i * 8];
    const bf16 hv = (bf16)v;
    Th[(size_t)(n0 + ty + i * 8) * K + k0 + tx] = hv;
    if constexpr (SPLIT)
      Tl[(size_t)(n0 + ty + i * 8) * K + k0 + tx] = (bf16)(v - (float)hv);
  }
}

// ---------------- bf16 MFMA GEMM, C = A(MxK) * BT(NxK)^T [+bias] ------------
// 128x128 tile, BK=32, 256 thr = 4 waves (2x2), wave tile 64x64 (4x4 frags).
// SPLIT: exact-ish fp32 via AhBh + AhBl + AlBh.
template<bool SPLIT, bool BIAS>
__global__ __launch_bounds__(256) void k_gemm(
    const bf16* __restrict__ Ah, const bf16* __restrict__ Al,
    const bf16* __restrict__ Bh, const bf16* __restrict__ Bl,
    const float* __restrict__ bias, float* __restrict__ C,
    int M, int N, int K) {
  __shared__ bf16 sAh[128 * 32];
  __shared__ bf16 sBh[128 * 32];
  __shared__ bf16 sAl[SPLIT ? 128 * 32 : 8];
  __shared__ bf16 sBl[SPLIT ? 128 * 32 : 8];

  const int tid  = threadIdx.x;
  const int lane = tid & 63;
  const int wave = tid >> 6;
  const int bm = blockIdx.y * 128;
  const int bn = blockIdx.x * 128;

  const int srow = tid >> 2;         // 0..63: staging row
  const int schk = (tid & 3) * 8;    // element offset in 32-wide K slab

  const bf16* gA0 = Ah + (size_t)(bm + srow) * K + schk;
  const bf16* gA1 = gA0 + (size_t)64 * K;
  const bf16* gB0 = Bh + (size_t)(bn + srow) * K + schk;
  const bf16* gB1 = gB0 + (size_t)64 * K;
  const bf16 *gA0l = nullptr, *gA1l = nullptr, *gB0l = nullptr, *gB1l = nullptr;
  if constexpr (SPLIT) {
    gA0l = Al + (size_t)(bm + srow) * K + schk;  gA1l = gA0l + (size_t)64 * K;
    gB0l = Bl + (size_t)(bn + srow) * K + schk;  gB1l = gB0l + (size_t)64 * K;
  }

  const int wm = (wave >> 1) * 64;
  const int wn = (wave & 1) * 64;
  const int lr = lane & 15;
  const int kg = lane >> 4;

  f32x4 acc[4][4] = {};

  for (int k0 = 0; k0 < K; k0 += 32) {
    __syncthreads();  // all ds_reads of prev iter done before restage
    gload16(gA0 + k0, &sAh[tid * 8]);
    gload16(gA1 + k0, &sAh[2048 + tid * 8]);
    gload16(gB0 + k0, &sBh[tid * 8]);
    gload16(gB1 + k0, &sBh[2048 + tid * 8]);
    if constexpr (SPLIT) {
      gload16(gA0l + k0, &sAl[tid * 8]);
      gload16(gA1l + k0, &sAl[2048 + tid * 8]);
      gload16(gB0l + k0, &sBl[tid * 8]);
      gload16(gB1l + k0, &sBl[2048 + tid * 8]);
    }
    __syncthreads();  // drains vmcnt(0): LDS tiles ready

    bf16x8 af[4], bfv[4];
#pragma unroll
    for (int i = 0; i < 4; i++)
      af[i] = *(const bf16x8*)&sAh[(wm + i * 16 + lr) * 32 + kg * 8];
#pragma unroll
    for (int i = 0; i < 4; i++)
      bfv[i] = *(const bf16x8*)&sBh[(wn + i * 16 + lr) * 32 + kg * 8];

#pragma unroll
    for (int mi = 0; mi < 4; mi++)
#pragma unroll
      for (int ni = 0; ni < 4; ni++)
        acc[mi][ni] = __builtin_amdgcn_mfma_f32_16x16x32_bf16(
            af[mi], bfv[ni], acc[mi][ni], 0, 0, 0);

    if constexpr (SPLIT) {
      bf16x8 afl[4], bfl[4];
#pragma unroll
      for (int i = 0; i < 4; i++)
        afl[i] = *(const bf16x8*)&sAl[(wm + i * 16 + lr) * 32 + kg * 8];
#pragma unroll
      for (int i = 0; i < 4; i++)
        bfl[i] = *(const bf16x8*)&sBl[(wn + i * 16 + lr) * 32 + kg * 8];
#pragma unroll
      for (int mi = 0; mi < 4; mi++)
#pragma unroll
        for (int ni = 0; ni < 4; ni++) {
          acc[mi][ni] = __builtin_amdgcn_mfma_f32_16x16x32_bf16(
              afl[mi], bfv[ni], acc[mi][ni], 0, 0, 0);
          acc[mi][ni] = __builtin_amdgcn_mfma_f32_16x16x32_bf16(
              af[mi], bfl[ni], acc[mi][ni], 0, 0, 0);
        }
    }
  }

  // epilogue: C/D layout col=lane&15, row=(lane>>4)*4+r  [m89-verified]
#pragma unroll
  for (int mi = 0; mi < 4; mi++) {
#pragma unroll
    for (int ni = 0; ni < 4; ni++) {
      const int col = bn + wn + ni * 16 + lr;
      float bv = 0.f;
      if constexpr (BIAS) bv = bias[col];
#pragma unroll
      for (int r = 0; r < 4; r++) {
        const int row = bm + wm + mi * 16 + kg * 4 + r;
        C[(size_t)row * N + col] = acc[mi][ni][r] + bv;
      }
    }
  }
}

// ---------------- depthwise causal conv (D_CONV=4) + silu -------------------
__global__ void k_conv(const float* __restrict__ xz, const float* __restrict__ cw,
                       const float* __restrict__ cb, float* __restrict__ xa) {
  const int bl = blockIdx.x;
  const int l  = bl & (L_SEQ - 1);
  for (int d = threadIdx.x; d < DINNER; d += blockDim.x) {
    float acc = cb[d];
#pragma unroll
    for (int k = 0; k < 4; k++) {
      const int ll = l + k - 3;
      if (ll >= 0)
        acc = fmaf(xz[(size_t)(bl + k - 3) * (2 * DINNER) + d], cw[d * 4 + k], acc);
    }
    xa[(size_t)bl * DINNER + d] = acc / (1.f + __expf(-acc));
  }
}

// ---------------- x_proj: dbl(2048,80) = xa(2048,1536) @ w(1536,80), fp32 ---
__global__ void k_xproj(const float* __restrict__ xa, const float* __restrict__ w,
                        float* __restrict__ dbl) {
  const int t = threadIdx.x;               // 640 = 8 rows x 80 cols
  const int r = blockIdx.x * 8 + t / 80;
  const int c = t % 80;
  const float* xr = xa + (size_t)r * DINNER;
  float acc = 0.f;
  for (int k = 0; k < DINNER; k++) acc = fmaf(xr[k], w[k * 80 + c], acc);
  dbl[(size_t)r * 80 + c] = acc;
}

// ---------------- dt_proj + softplus, fp32 ----------------------------------
__global__ void k_dtproj(const float* __restrict__ dbl, const float* __restrict__ w,
                         const float* __restrict__ bvec, float* __restrict__ dt) {
  const int r = blockIdx.x;
  __shared__ float ds[DTRANK];
  if (threadIdx.x < DTRANK) ds[threadIdx.x] = dbl[(size_t)r * 80 + threadIdx.x];
  __syncthreads();
  for (int c = threadIdx.x; c < DINNER; c += blockDim.x) {
    float acc = bvec[c];
#pragma unroll
    for (int k = 0; k < DTRANK; k++) acc = fmaf(ds[k], w[k * DINNER + c], acc);
    dt[(size_t)r * DINNER + c] = (acc > 20.f) ? acc : log1pf(expf(acc));
  }
}

// ---------------- selective scan + (ys + xa*D)*silu(z), fused ---------------
// lane = (d%16 group)*16-state; one lane per (b,d,n); 16-lane shfl reduce.
__global__ void k_scan(const float* __restrict__ dt, const float* __restrict__ dbl,
                       const float* __restrict__ xa, const float* __restrict__ a_log,
                       const float* __restrict__ dvec, const float* __restrict__ xz,
                       float* __restrict__ ycmb) {
  const int b  = blockIdx.y;
  const int n  = threadIdx.x & 15;
  const int dl = threadIdx.x >> 4;
  const int d  = blockIdx.x * 16 + dl;
  const float a  = -expf(a_log[d * DSTATE + n]);
  const float Dv = dvec[d];
  float h = 0.f;
  const size_t rb = (size_t)b * L_SEQ;
  for (int l = 0; l < L_SEQ; l++) {
    const size_t rl = rb + l;
    const float dtv = dt[rl * DINNER + d];
    const float xav = xa[rl * DINNER + d];
    const float Bv  = dbl[rl * 80 + DTRANK + n];
    const float Cv  = dbl[rl * 80 + DTRANK + DSTATE + n];
    const float dA  = __expf(dtv * a);
    h = dA * h + dtv * Bv * xav;
    float y = h * Cv;
    y += __shfl_xor(y, 1);
    y += __shfl_xor(y, 2);
    y += __shfl_xor(y, 4);
    y += __shfl_xor(y, 8);
    if (n == 0) {
      const float z  = xz[rl * (2 * DINNER) + DINNER + d];
      const float sz = z / (1.f + __expf(-z));
      ycmb[rl * DINNER + d] = (y + xav * Dv) * sz;
    }
  }
}

// ============================================================================
extern "C" void kernel_launch(void* const* d_in, const int* in_sizes, int n_in,
                              void* d_out, int out_size, void* d_ws, size_t ws_size,
                              hipStream_t stream) {
  const int*   ids   = (const int*)d_in[0];
  const float* emb   = (const float*)d_in[1];
  const float* w_in  = (const float*)d_in[2];   // 768 x 3072
  const float* cw    = (const float*)d_in[3];   // 1536 x 4
  const float* cb    = (const float*)d_in[4];
  const float* w_x   = (const float*)d_in[5];   // 1536 x 80
  const float* w_dt  = (const float*)d_in[6];   // 48 x 1536
  const float* b_dt  = (const float*)d_in[7];
  const float* a_log = (const float*)d_in[8];   // 1536 x 16
  const float* dvec  = (const float*)d_in[9];
  const float* w_out = (const float*)d_in[10];  // 1536 x 768
  const float* w_lm  = (const float*)d_in[11];  // 768 x 32000
  const float* b_lm  = (const float*)d_in[12];
  float* out = (float*)d_out;

  char* ws = (char*)d_ws;
  size_t off = 0;
  auto alloc = [&](size_t bytes) {
    void* p = ws + off;
    off = (off + bytes + 255) & ~(size_t)255;
    return p;
  };
  float* xw    = (float*)alloc((size_t)BL * DMODEL * 4);
  float* xz    = (float*)alloc((size_t)BL * 2 * DINNER * 4);
  float* xa    = (float*)alloc((size_t)BL * DINNER * 4);
  float* dbl   = (float*)alloc((size_t)BL * 80 * 4);
  float* dt    = (float*)alloc((size_t)BL * DINNER * 4);
  float* ycmb  = (float*)alloc((size_t)BL * DINNER * 4);
  float* yo    = (float*)alloc((size_t)BL * DMODEL * 4);
  bf16* xwh    = (bf16*)alloc((size_t)BL * DMODEL * 2);
  bf16* xwl    = (bf16*)alloc((size_t)BL * DMODEL * 2);
  bf16* wtinh  = (bf16*)alloc((size_t)3072 * DMODEL * 2);
  bf16* wtinl  = (bf16*)alloc((size_t)3072 * DMODEL * 2);
  bf16* ych    = (bf16*)alloc((size_t)BL * DINNER * 2);
  bf16* ycl    = (bf16*)alloc((size_t)BL * DINNER * 2);
  bf16* wtoh   = (bf16*)alloc((size_t)DMODEL * DINNER * 2);
  bf16* wtol   = (bf16*)alloc((size_t)DMODEL * DINNER * 2);
  bf16* yob    = (bf16*)alloc((size_t)BL * DMODEL * 2);
  bf16* wtlm   = (bf16*)alloc((size_t)VOCAB * DMODEL * 2);
  if (off > ws_size) {
    fprintf(stderr, "kernel_launch: ws too small (need %zu, have %zu)\n", off, ws_size);
    return;
  }

  // 1. embed
  k_embed<<<BL, 192, 0, stream>>>(ids, emb, xw);
  // 2. split activations + transpose-convert in_proj weight
  k_split4<<<(BL * DMODEL / 4 + 255) / 256, 256, 0, stream>>>(xw, xwh, xwl, BL * DMODEL / 4);
  k_tconv<true><<<dim3(3072 / 32, DMODEL / 32), dim3(32, 8), 0, stream>>>(w_in, wtinh, wtinl, DMODEL, 3072);
  // 3. in_proj GEMM (split, fp32-exact-ish): xz = xw @ w_in
  k_gemm<true, false><<<dim3(3072 / 128, BL / 128), 256, 0, stream>>>(
      xwh, xwl, wtinh, wtinl, nullptr, xz, BL, 3072, DMODEL);
  // 4. conv + silu
  k_conv<<<BL, 256, 0, stream>>>(xz, cw, cb, xa);
  // 5. x_proj (fp32)
  k_xproj<<<BL / 8, 640, 0, stream>>>(xa, w_x, dbl);
  // 6. dt_proj + softplus (fp32)
  k_dtproj<<<BL, 256, 0, stream>>>(dbl, w_dt, b_dt, dt);
  // 7. scan + combine (fp32)
  k_scan<<<dim3(DINNER / 16, B_SZ), 256, 0, stream>>>(dt, dbl, xa, a_log, dvec, xz, ycmb);
  // 8. out_proj GEMM (split): yo = ycmb @ w_out
  k_split4<<<(BL * DINNER / 4 + 255) / 256, 256, 0, stream>>>(ycmb, ych, ycl, BL * DINNER / 4);
  k_tconv<true><<<dim3(DMODEL / 32, DINNER / 32), dim3(32, 8), 0, stream>>>(w_out, wtoh, wtol, DINNER, DMODEL);
  k_gemm<true, false><<<dim3(DMODEL / 128, BL / 128), 256, 0, stream>>>(
      ych, ycl, wtoh, wtol, nullptr, yo, BL, DMODEL, DINNER);
  // 9. lm_head GEMM (single bf16 + fp32 bias): out = yo @ w_lm + b_lm
  k_cvt4<<<(BL * DMODEL / 4 + 255) / 256, 256, 0, stream>>>(yo, yob, BL * DMODEL / 4);
  k_tconv<false><<<dim3(VOCAB / 32, DMODEL / 32), dim3(32, 8), 0, stream>>>(w_lm, wtlm, nullptr, DMODEL, VOCAB);
  k_gemm<false, true><<<dim3(VOCAB / 128, BL / 128), 256, 0, stream>>>(
      yob, nullptr, wtlm, nullptr, b_lm, out, BL, VOCAB, DMODEL);
}

// Round 2
// 607.692 us; speedup vs baseline: 2.1247x; 2.1247x over previous
//
#include <hip/hip_runtime.h>
#include <hip/hip_bf16.h>
#include <cstdio>
#include <cstdint>

#define B_SZ    2
#define L_SEQ   1024
#define DMODEL  768
#define DINNER  1536
#define DSTATE  16
#define DTRANK  48
#define VOCAB   32000
#define BL      (B_SZ * L_SEQ)   // 2048
#define NCH     64               // scan chunks per sequence
#define CLEN    16               // timesteps per chunk (NCH*CLEN == L_SEQ)

typedef __bf16 bf16;
typedef __bf16 bf16x8 __attribute__((ext_vector_type(8)));
typedef __bf16 bf16x4 __attribute__((ext_vector_type(4)));
typedef float  f32x4  __attribute__((ext_vector_type(4)));

// ---------------- async global->LDS (16B/lane, wave-uniform base + lane*16) --
__device__ __forceinline__ void gload16(const void* g, void* l) {
  __builtin_amdgcn_global_load_lds(
      (const __attribute__((address_space(1))) void*)g,
      (__attribute__((address_space(3))) void*)l, 16, 0, 0);
}

// ---------------- embedding gather ------------------------------------------
__global__ void k_embed(const int* __restrict__ ids, const float* __restrict__ emb,
                        float* __restrict__ xw) {
  const int row = blockIdx.x;
  const int id  = ids[row];
  const float4* s = (const float4*)(emb + (size_t)id * DMODEL);
  float4* d = (float4*)(xw + (size_t)row * DMODEL);
  for (int i = threadIdx.x; i < DMODEL / 4; i += blockDim.x) d[i] = s[i];
}

// ---------------- f32 -> bf16 hi/lo split (activations) ---------------------
__global__ void k_split4(const float* __restrict__ x, bf16* __restrict__ h,
                         bf16* __restrict__ l, int n4) {
  const int i = blockIdx.x * blockDim.x + threadIdx.x;
  if (i >= n4) return;
  const float4 v = ((const float4*)x)[i];
  bf16x4 hv, lv;
  hv[0] = (bf16)v.x; hv[1] = (bf16)v.y; hv[2] = (bf16)v.z; hv[3] = (bf16)v.w;
  lv[0] = (bf16)(v.x - (float)hv[0]); lv[1] = (bf16)(v.y - (float)hv[1]);
  lv[2] = (bf16)(v.z - (float)hv[2]); lv[3] = (bf16)(v.w - (float)hv[3]);
  *(bf16x4*)(h + (size_t)i * 4) = hv;
  *(bf16x4*)(l + (size_t)i * 4) = lv;
}

__global__ void k_cvt4(const float* __restrict__ x, bf16* __restrict__ h, int n4) {
  const int i = blockIdx.x * blockDim.x + threadIdx.x;
  if (i >= n4) return;
  const float4 v = ((const float4*)x)[i];
  bf16x4 hv;
  hv[0] = (bf16)v.x; hv[1] = (bf16)v.y; hv[2] = (bf16)v.z; hv[3] = (bf16)v.w;
  *(bf16x4*)(h + (size_t)i * 4) = hv;
}

// ---------------- weight transpose + convert: W(K,N) f32 -> WT(N,K) bf16 ----
template<bool SPLIT>
__global__ void k_tconv(const float* __restrict__ W, bf16* __restrict__ Th,
                        bf16* __restrict__ Tl, int K, int N) {
  __shared__ float t[32][33];
  const int n0 = blockIdx.x * 32;
  const int k0 = blockIdx.y * 32;
  const int tx = threadIdx.x;   // 0..31
  const int ty = threadIdx.y;   // 0..7
#pragma unroll
  for (int i = 0; i < 4; i++)
    t[ty + i * 8][tx] = W[(size_t)(k0 + ty + i * 8) * N + n0 + tx];
  __syncthreads();
#pragma unroll
  for (int i = 0; i < 4; i++) {
    const float v = t[tx][ty + i * 8];
    const bf16 hv = (bf16)v;
    Th[(size_t)(n0 + ty + i * 8) * K + k0 + tx] = hv;
    if constexpr (SPLIT)
      Tl[(size_t)(n0 + ty + i * 8) * K + k0 + tx] = (bf16)(v - (float)hv);
  }
}

// ---------------- bf16 MFMA GEMM, C = A(MxK) * BT(NxK)^T [+bias] ------------
// 128x128 tile, BK=32, 256 thr = 4 waves (2x2), wave tile 64x64 (4x4 frags).
// SPLIT: exact-ish fp32 via AhBh + AhBl + AlBh.
template<bool SPLIT, bool BIAS>
__global__ __launch_bounds__(256) void k_gemm(
    const bf16* __restrict__ Ah, const bf16* __restrict__ Al,
    const bf16* __restrict__ Bh, const bf16* __restrict__ Bl,
    const float* __restrict__ bias, float* __restrict__ C,
    int M, int N, int K) {
  __shared__ bf16 sAh[128 * 32];
  __shared__ bf16 sBh[128 * 32];
  __shared__ bf16 sAl[SPLIT ? 128 * 32 : 8];
  __shared__ bf16 sBl[SPLIT ? 128 * 32 : 8];

  const int tid  = threadIdx.x;
  const int lane = tid & 63;
  const int wave = tid >> 6;
  const int bm = blockIdx.y * 128;
  const int bn = blockIdx.x * 128;

  const int srow = tid >> 2;         // 0..63: staging row
  const int schk = (tid & 3) * 8;    // element offset in 32-wide K slab

  const bf16* gA0 = Ah + (size_t)(bm + srow) * K + schk;
  const bf16* gA1 = gA0 + (size_t)64 * K;
  const bf16* gB0 = Bh + (size_t)(bn + srow) * K + schk;
  const bf16* gB1 = gB0 + (size_t)64 * K;
  const bf16 *gA0l = nullptr, *gA1l = nullptr, *gB0l = nullptr, *gB1l = nullptr;
  if constexpr (SPLIT) {
    gA0l = Al + (size_t)(bm + srow) * K + schk;  gA1l = gA0l + (size_t)64 * K;
    gB0l = Bl + (size_t)(bn + srow) * K + schk;  gB1l = gB0l + (size_t)64 * K;
  }

  const int wm = (wave >> 1) * 64;
  const int wn = (wave & 1) * 64;
  const int lr = lane & 15;
  const int kg = lane >> 4;

  f32x4 acc[4][4] = {};

  for (int k0 = 0; k0 < K; k0 += 32) {
    __syncthreads();  // all ds_reads of prev iter done before restage
    gload16(gA0 + k0, &sAh[tid * 8]);
    gload16(gA1 + k0, &sAh[2048 + tid * 8]);
    gload16(gB0 + k0, &sBh[tid * 8]);
    gload16(gB1 + k0, &sBh[2048 + tid * 8]);
    if constexpr (SPLIT) {
      gload16(gA0l + k0, &sAl[tid * 8]);
      gload16(gA1l + k0, &sAl[2048 + tid * 8]);
      gload16(gB0l + k0, &sBl[tid * 8]);
      gload16(gB1l + k0, &sBl[2048 + tid * 8]);
    }
    __syncthreads();  // drains vmcnt(0): LDS tiles ready

    bf16x8 af[4], bfv[4];
#pragma unroll
    for (int i = 0; i < 4; i++)
      af[i] = *(const bf16x8*)&sAh[(wm + i * 16 + lr) * 32 + kg * 8];
#pragma unroll
    for (int i = 0; i < 4; i++)
      bfv[i] = *(const bf16x8*)&sBh[(wn + i * 16 + lr) * 32 + kg * 8];

#pragma unroll
    for (int mi = 0; mi < 4; mi++)
#pragma unroll
      for (int ni = 0; ni < 4; ni++)
        acc[mi][ni] = __builtin_amdgcn_mfma_f32_16x16x32_bf16(
            af[mi], bfv[ni], acc[mi][ni], 0, 0, 0);

    if constexpr (SPLIT) {
      bf16x8 afl[4], bfl[4];
#pragma unroll
      for (int i = 0; i < 4; i++)
        afl[i] = *(const bf16x8*)&sAl[(wm + i * 16 + lr) * 32 + kg * 8];
#pragma unroll
      for (int i = 0; i < 4; i++)
        bfl[i] = *(const bf16x8*)&sBl[(wn + i * 16 + lr) * 32 + kg * 8];
#pragma unroll
      for (int mi = 0; mi < 4; mi++)
#pragma unroll
        for (int ni = 0; ni < 4; ni++) {
          acc[mi][ni] = __builtin_amdgcn_mfma_f32_16x16x32_bf16(
              afl[mi], bfv[ni], acc[mi][ni], 0, 0, 0);
          acc[mi][ni] = __builtin_amdgcn_mfma_f32_16x16x32_bf16(
              af[mi], bfl[ni], acc[mi][ni], 0, 0, 0);
        }
    }
  }

  // epilogue: C/D layout col=lane&15, row=(lane>>4)*4+r  [m89-verified]
#pragma unroll
  for (int mi = 0; mi < 4; mi++) {
#pragma unroll
    for (int ni = 0; ni < 4; ni++) {
      const int col = bn + wn + ni * 16 + lr;
      float bv = 0.f;
      if constexpr (BIAS) bv = bias[col];
#pragma unroll
      for (int r = 0; r < 4; r++) {
        const int row = bm + wm + mi * 16 + kg * 4 + r;
        C[(size_t)row * N + col] = acc[mi][ni][r] + bv;
      }
    }
  }
}

// ---------------- depthwise causal conv (D_CONV=4) + silu -------------------
__global__ void k_conv(const float* __restrict__ xz, const float* __restrict__ cw,
                       const float* __restrict__ cb, float* __restrict__ xa) {
  const int bl = blockIdx.x;
  const int l  = bl & (L_SEQ - 1);
  for (int d = threadIdx.x; d < DINNER; d += blockDim.x) {
    float acc = cb[d];
#pragma unroll
    for (int k = 0; k < 4; k++) {
      const int ll = l + k - 3;
      if (ll >= 0)
        acc = fmaf(xz[(size_t)(bl + k - 3) * (2 * DINNER) + d], cw[d * 4 + k], acc);
    }
    xa[(size_t)bl * DINNER + d] = acc / (1.f + __expf(-acc));
  }
}

// ---------------- x_proj: dbl(2048,80) = xa(2048,1536) @ w(1536,80), fp32 ---
__global__ void k_xproj(const float* __restrict__ xa, const float* __restrict__ w,
                        float* __restrict__ dbl) {
  const int t = threadIdx.x;               // 640 = 8 rows x 80 cols
  const int r = blockIdx.x * 8 + t / 80;
  const int c = t % 80;
  const float* xr = xa + (size_t)r * DINNER;
  float acc = 0.f;
  for (int k = 0; k < DINNER; k++) acc = fmaf(xr[k], w[k * 80 + c], acc);
  dbl[(size_t)r * 80 + c] = acc;
}

// ---------------- dt_proj + softplus, fp32 ----------------------------------
__global__ void k_dtproj(const float* __restrict__ dbl, const float* __restrict__ w,
                         const float* __restrict__ bvec, float* __restrict__ dt) {
  const int r = blockIdx.x;
  __shared__ float ds[DTRANK];
  if (threadIdx.x < DTRANK) ds[threadIdx.x] = dbl[(size_t)r * 80 + threadIdx.x];
  __syncthreads();
  for (int c = threadIdx.x; c < DINNER; c += blockDim.x) {
    float acc = bvec[c];
#pragma unroll
    for (int k = 0; k < DTRANK; k++) acc = fmaf(ds[k], w[k * DINNER + c], acc);
    dt[(size_t)r * DINNER + c] = (acc > 20.f) ? acc : log1pf(expf(acc));
  }
}

// ======================= chunk-parallel selective scan =======================
// h_l = dA_l*h_{l-1} + dBu_l is linear -> split L into NCH chunks of CLEN.
// Pass 1: per (b,d,chunk) lane: local scan (h0=0) -> S, and P = prod(dA).
// Pass 2: per (b,d,n): H_c = S_{c-1} + P_{c-1}*H_{c-1} over chunks (64 steps).
// Pass 3: per (b,d,chunk) lane: re-scan with h0=H_c, y = sum_n h[n]*C[n],
//         fused epilogue (y + xa*D)*silu(z).
// Lane owns d (coalesced dt/xa); h[16]/p[16]/a[16] in registers (static idx).

__global__ __launch_bounds__(256) void k_scan1(
    const float* __restrict__ dt, const float* __restrict__ dbl,
    const float* __restrict__ xa, const float* __restrict__ a_log,
    float* __restrict__ P, float* __restrict__ S) {
  const int tid = threadIdx.x;
  const int d = blockIdx.x * 256 + tid;
  const int c = blockIdx.y;
  const int b = blockIdx.z;
  __shared__ float sB[CLEN][DSTATE];
  {
    const int j = tid >> 4, n = tid & 15;
    sB[j][n] = dbl[(size_t)(b * L_SEQ + c * CLEN + j) * 80 + DTRANK + n];
  }
  __syncthreads();
  float a[16];
#pragma unroll
  for (int q = 0; q < 4; q++) {
    const float4 v = *(const float4*)&a_log[d * DSTATE + q * 4];
    a[q*4+0] = -expf(v.x); a[q*4+1] = -expf(v.y);
    a[q*4+2] = -expf(v.z); a[q*4+3] = -expf(v.w);
  }
  float h[16] = {}, p[16];
#pragma unroll
  for (int n = 0; n < 16; n++) p[n] = 1.f;
  const size_t rowb = (size_t)(b * L_SEQ + c * CLEN);
#pragma unroll 4
  for (int j = 0; j < CLEN; j++) {
    const size_t row = rowb + j;
    const float dtv = dt[row * DINNER + d];
    const float xav = xa[row * DINNER + d];
    const float du  = dtv * xav;
#pragma unroll
    for (int n = 0; n < 16; n++) {
      const float dA = __expf(dtv * a[n]);
      h[n] = fmaf(dA, h[n], du * sB[j][n]);
      p[n] *= dA;
    }
  }
  const size_t base = (((size_t)c * B_SZ + b) * DINNER + d) * DSTATE;
#pragma unroll
  for (int q = 0; q < 4; q++) {
    *(float4*)&P[base + q * 4] = make_float4(p[q*4], p[q*4+1], p[q*4+2], p[q*4+3]);
    *(float4*)&S[base + q * 4] = make_float4(h[q*4], h[q*4+1], h[q*4+2], h[q*4+3]);
  }
}

__global__ __launch_bounds__(256) void k_scan2(
    const float* __restrict__ P, const float* __restrict__ S,
    float* __restrict__ Hin) {
  const int gid = blockIdx.x * 256 + threadIdx.x;   // (b*DINNER+d)*16+n
  const int STRIDE = B_SZ * DINNER * DSTATE;        // 49152
  float h = 0.f;
#pragma unroll 4
  for (int c = 0; c < NCH; c++) {
    Hin[(size_t)c * STRIDE + gid] = h;
    h = fmaf(P[(size_t)c * STRIDE + gid], h, S[(size_t)c * STRIDE + gid]);
  }
}

__global__ __launch_bounds__(256) void k_scan3(
    const float* __restrict__ dt, const float* __restrict__ dbl,
    const float* __restrict__ xa, const float* __restrict__ a_log,
    const float* __restrict__ dvec, const float* __restrict__ xz,
    const float* __restrict__ Hin, float* __restrict__ ycmb) {
  const int tid = threadIdx.x;
  const int d = blockIdx.x * 256 + tid;
  const int c = blockIdx.y;
  const int b = blockIdx.z;
  __shared__ float sB[CLEN][DSTATE];
  __shared__ float sC[CLEN][DSTATE];
  {
    const int j = tid >> 4, n = tid & 15;
    const size_t r80 = (size_t)(b * L_SEQ + c * CLEN + j) * 80;
    sB[j][n] = dbl[r80 + DTRANK + n];
    sC[j][n] = dbl[r80 + DTRANK + DSTATE + n];
  }
  __syncthreads();
  float a[16];
#pragma unroll
  for (int q = 0; q < 4; q++) {
    const float4 v = *(const float4*)&a_log[d * DSTATE + q * 4];
    a[q*4+0] = -expf(v.x); a[q*4+1] = -expf(v.y);
    a[q*4+2] = -expf(v.z); a[q*4+3] = -expf(v.w);
  }
  float h[16];
  const size_t base = (((size_t)c * B_SZ + b) * DINNER + d) * DSTATE;
#pragma unroll
  for (int q = 0; q < 4; q++) {
    const float4 v = *(const float4*)&Hin[base + q * 4];
    h[q*4+0] = v.x; h[q*4+1] = v.y; h[q*4+2] = v.z; h[q*4+3] = v.w;
  }
  const float Dv = dvec[d];
  const size_t rowb = (size_t)(b * L_SEQ + c * CLEN);
#pragma unroll 4
  for (int j = 0; j < CLEN; j++) {
    const size_t row = rowb + j;
    const float dtv = dt[row * DINNER + d];
    const float xav = xa[row * DINNER + d];
    const float du  = dtv * xav;
    float y = 0.f;
#pragma unroll
    for (int n = 0; n < 16; n++) {
      const float dA = __expf(dtv * a[n]);
      h[n] = fmaf(dA, h[n], du * sB[j][n]);
      y = fmaf(h[n], sC[j][n], y);
    }
    const float z  = xz[row * (2 * DINNER) + DINNER + d];
    const float sz = z / (1.f + __expf(-z));
    ycmb[row * DINNER + d] = fmaf(xav, Dv, y) * sz;
  }
}

// ============================================================================
extern "C" void kernel_launch(void* const* d_in, const int* in_sizes, int n_in,
                              void* d_out, int out_size, void* d_ws, size_t ws_size,
                              hipStream_t stream) {
  const int*   ids   = (const int*)d_in[0];
  const float* emb   = (const float*)d_in[1];
  const float* w_in  = (const float*)d_in[2];   // 768 x 3072
  const float* cw    = (const float*)d_in[3];   // 1536 x 4
  const float* cb    = (const float*)d_in[4];
  const float* w_x   = (const float*)d_in[5];   // 1536 x 80
  const float* w_dt  = (const float*)d_in[6];   // 48 x 1536
  const float* b_dt  = (const float*)d_in[7];
  const float* a_log = (const float*)d_in[8];   // 1536 x 16
  const float* dvec  = (const float*)d_in[9];
  const float* w_out = (const float*)d_in[10];  // 1536 x 768
  const float* w_lm  = (const float*)d_in[11];  // 768 x 32000
  const float* b_lm  = (const float*)d_in[12];
  float* out = (float*)d_out;

  char* ws = (char*)d_ws;
  size_t off = 0;
  auto alloc = [&](size_t bytes) {
    void* p = ws + off;
    off = (off + bytes + 255) & ~(size_t)255;
    return p;
  };
  float* xw    = (float*)alloc((size_t)BL * DMODEL * 4);
  float* xz    = (float*)alloc((size_t)BL * 2 * DINNER * 4);
  float* xa    = (float*)alloc((size_t)BL * DINNER * 4);
  float* dbl   = (float*)alloc((size_t)BL * 80 * 4);
  float* dt    = (float*)alloc((size_t)BL * DINNER * 4);
  float* ycmb  = (float*)alloc((size_t)BL * DINNER * 4);
  float* yo    = (float*)alloc((size_t)BL * DMODEL * 4);
  bf16* xwh    = (bf16*)alloc((size_t)BL * DMODEL * 2);
  bf16* xwl    = (bf16*)alloc((size_t)BL * DMODEL * 2);
  bf16* wtinh  = (bf16*)alloc((size_t)3072 * DMODEL * 2);
  bf16* wtinl  = (bf16*)alloc((size_t)3072 * DMODEL * 2);
  bf16* ych    = (bf16*)alloc((size_t)BL * DINNER * 2);
  bf16* ycl    = (bf16*)alloc((size_t)BL * DINNER * 2);
  bf16* wtoh   = (bf16*)alloc((size_t)DMODEL * DINNER * 2);
  bf16* wtol   = (bf16*)alloc((size_t)DMODEL * DINNER * 2);
  bf16* yob    = (bf16*)alloc((size_t)BL * DMODEL * 2);
  bf16* wtlm   = (bf16*)alloc((size_t)VOCAB * DMODEL * 2);
  if (off > ws_size) {
    fprintf(stderr, "kernel_launch: ws too small (need %zu, have %zu)\n", off, ws_size);
    return;
  }

  // Scan scratch (12.58 MB each) aliased onto dead-lifetime regions:
  //  P   -> [xwh..wtinl]  (15.73 MB; dead after in_proj GEMM, scan runs later)
  //  S   -> [ych..wtol]   (17.30 MB; written only after scan completes)
  //  Hin -> wtlm          (49.15 MB; written only after scan completes)
  float* Pbuf = (float*)xwh;
  float* Sbuf = (float*)ych;
  float* Hin  = (float*)wtlm;

  // 1. embed
  k_embed<<<BL, 192, 0, stream>>>(ids, emb, xw);
  // 2. split activations + transpose-convert in_proj weight
  k_split4<<<(BL * DMODEL / 4 + 255) / 256, 256, 0, stream>>>(xw, xwh, xwl, BL * DMODEL / 4);
  k_tconv<true><<<dim3(3072 / 32, DMODEL / 32), dim3(32, 8), 0, stream>>>(w_in, wtinh, wtinl, DMODEL, 3072);
  // 3. in_proj GEMM (split, fp32-exact-ish): xz = xw @ w_in
  k_gemm<true, false><<<dim3(3072 / 128, BL / 128), 256, 0, stream>>>(
      xwh, xwl, wtinh, wtinl, nullptr, xz, BL, 3072, DMODEL);
  // 4. conv + silu
  k_conv<<<BL, 256, 0, stream>>>(xz, cw, cb, xa);
  // 5. x_proj (fp32)
  k_xproj<<<BL / 8, 640, 0, stream>>>(xa, w_x, dbl);
  // 6. dt_proj + softplus (fp32)
  k_dtproj<<<BL, 256, 0, stream>>>(dbl, w_dt, b_dt, dt);
  // 7. chunk-parallel scan + fused combine epilogue (fp32)
  k_scan1<<<dim3(DINNER / 256, NCH, B_SZ), 256, 0, stream>>>(dt, dbl, xa, a_log, Pbuf, Sbuf);
  k_scan2<<<(B_SZ * DINNER * DSTATE) / 256, 256, 0, stream>>>(Pbuf, Sbuf, Hin);
  k_scan3<<<dim3(DINNER / 256, NCH, B_SZ), 256, 0, stream>>>(dt, dbl, xa, a_log, dvec, xz, Hin, ycmb);
  // 8. out_proj GEMM (split): yo = ycmb @ w_out
  k_split4<<<(BL * DINNER / 4 + 255) / 256, 256, 0, stream>>>(ycmb, ych, ycl, BL * DINNER / 4);
  k_tconv<true><<<dim3(DMODEL / 32, DINNER / 32), dim3(32, 8), 0, stream>>>(w_out, wtoh, wtol, DINNER, DMODEL);
  k_gemm<true, false><<<dim3(DMODEL / 128, BL / 128), 256, 0, stream>>>(
      ych, ycl, wtoh, wtol, nullptr, yo, BL, DMODEL, DINNER);
  // 9. lm_head GEMM (single bf16 + fp32 bias): out = yo @ w_lm + b_lm
  k_cvt4<<<(BL * DMODEL / 4 + 255) / 256, 256, 0, stream>>>(yo, yob, BL * DMODEL / 4);
  k_tconv<false><<<dim3(VOCAB / 32, DMODEL / 32), dim3(32, 8), 0, stream>>>(w_lm, wtlm, nullptr, DMODEL, VOCAB);
  k_gemm<false, true><<<dim3(VOCAB / 128, BL / 128), 256, 0, stream>>>(
      yob, nullptr, wtlm, nullptr, b_lm, out, BL, VOCAB, DMODEL);
}

// Round 4
// 571.023 us; speedup vs baseline: 2.2611x; 1.0642x over previous
//
#include <hip/hip_runtime.h>
#include <hip/hip_bf16.h>
#include <cstdio>
#include <cstdint>

#define B_SZ    2
#define L_SEQ   1024
#define DMODEL  768
#define DINNER  1536
#define DSTATE  16
#define DTRANK  48
#define VOCAB   32000
#define BL      (B_SZ * L_SEQ)   // 2048
#define NCH     64               // scan chunks per sequence
#define CLEN    16               // timesteps per chunk (NCH*CLEN == L_SEQ)

typedef __bf16 bf16;
typedef __bf16 bf16x8 __attribute__((ext_vector_type(8)));
typedef __bf16 bf16x4 __attribute__((ext_vector_type(4)));
typedef float  f32x4  __attribute__((ext_vector_type(4)));

// ---------------- async global->LDS (16B/lane, wave-uniform base + lane*16) --
__device__ __forceinline__ void gload16(const void* g, void* l) {
  __builtin_amdgcn_global_load_lds(
      (const __attribute__((address_space(1))) void*)g,
      (__attribute__((address_space(3))) void*)l, 16, 0, 0);
}

// ---------------- embedding gather ------------------------------------------
__global__ void k_embed(const int* __restrict__ ids, const float* __restrict__ emb,
                        float* __restrict__ xw) {
  const int row = blockIdx.x;
  const int id  = ids[row];
  const float4* s = (const float4*)(emb + (size_t)id * DMODEL);
  float4* d = (float4*)(xw + (size_t)row * DMODEL);
  for (int i = threadIdx.x; i < DMODEL / 4; i += blockDim.x) d[i] = s[i];
}

// ---------------- f32 -> bf16 hi/lo split (activations) ---------------------
__global__ void k_split4(const float* __restrict__ x, bf16* __restrict__ h,
                         bf16* __restrict__ l, int n4) {
  const int i = blockIdx.x * blockDim.x + threadIdx.x;
  if (i >= n4) return;
  const float4 v = ((const float4*)x)[i];
  bf16x4 hv, lv;
  hv[0] = (bf16)v.x; hv[1] = (bf16)v.y; hv[2] = (bf16)v.z; hv[3] = (bf16)v.w;
  lv[0] = (bf16)(v.x - (float)hv[0]); lv[1] = (bf16)(v.y - (float)hv[1]);
  lv[2] = (bf16)(v.z - (float)hv[2]); lv[3] = (bf16)(v.w - (float)hv[3]);
  *(bf16x4*)(h + (size_t)i * 4) = hv;
  *(bf16x4*)(l + (size_t)i * 4) = lv;
}

__global__ void k_cvt4(const float* __restrict__ x, bf16* __restrict__ h, int n4) {
  const int i = blockIdx.x * blockDim.x + threadIdx.x;
  if (i >= n4) return;
  const float4 v = ((const float4*)x)[i];
  bf16x4 hv;
  hv[0] = (bf16)v.x; hv[1] = (bf16)v.y; hv[2] = (bf16)v.z; hv[3] = (bf16)v.w;
  *(bf16x4*)(h + (size_t)i * 4) = hv;
}

// ---------------- weight transpose + convert: W(K,N) f32 -> WT(N,K) bf16 ----
template<bool SPLIT>
__global__ void k_tconv(const float* __restrict__ W, bf16* __restrict__ Th,
                        bf16* __restrict__ Tl, int K, int N) {
  __shared__ float t[32][33];
  const int n0 = blockIdx.x * 32;
  const int k0 = blockIdx.y * 32;
  const int tx = threadIdx.x;   // 0..31
  const int ty = threadIdx.y;   // 0..7
#pragma unroll
  for (int i = 0; i < 4; i++)
    t[ty + i * 8][tx] = W[(size_t)(k0 + ty + i * 8) * N + n0 + tx];
  __syncthreads();
#pragma unroll
  for (int i = 0; i < 4; i++) {
    const float v = t[tx][ty + i * 8];
    const bf16 hv = (bf16)v;
    Th[(size_t)(n0 + ty + i * 8) * K + k0 + tx] = hv;
    if constexpr (SPLIT)
      Tl[(size_t)(n0 + ty + i * 8) * K + k0 + tx] = (bf16)(v - (float)hv);
  }
}

// ---------------- bf16 MFMA GEMM (old 128x128 2-barrier), SPLIT variants ----
template<bool SPLIT, bool BIAS>
__global__ __launch_bounds__(256) void k_gemm(
    const bf16* __restrict__ Ah, const bf16* __restrict__ Al,
    const bf16* __restrict__ Bh, const bf16* __restrict__ Bl,
    const float* __restrict__ bias, float* __restrict__ C,
    int M, int N, int K) {
  __shared__ bf16 sAh[128 * 32];
  __shared__ bf16 sBh[128 * 32];
  __shared__ bf16 sAl[SPLIT ? 128 * 32 : 8];
  __shared__ bf16 sBl[SPLIT ? 128 * 32 : 8];

  const int tid  = threadIdx.x;
  const int lane = tid & 63;
  const int wave = tid >> 6;
  const int bm = blockIdx.y * 128;
  const int bn = blockIdx.x * 128;

  const int srow = tid >> 2;         // 0..63: staging row
  const int schk = (tid & 3) * 8;    // element offset in 32-wide K slab

  const bf16* gA0 = Ah + (size_t)(bm + srow) * K + schk;
  const bf16* gA1 = gA0 + (size_t)64 * K;
  const bf16* gB0 = Bh + (size_t)(bn + srow) * K + schk;
  const bf16* gB1 = gB0 + (size_t)64 * K;
  const bf16 *gA0l = nullptr, *gA1l = nullptr, *gB0l = nullptr, *gB1l = nullptr;
  if constexpr (SPLIT) {
    gA0l = Al + (size_t)(bm + srow) * K + schk;  gA1l = gA0l + (size_t)64 * K;
    gB0l = Bl + (size_t)(bn + srow) * K + schk;  gB1l = gB0l + (size_t)64 * K;
  }

  const int wm = (wave >> 1) * 64;
  const int wn = (wave & 1) * 64;
  const int lr = lane & 15;
  const int kg = lane >> 4;

  f32x4 acc[4][4] = {};

  for (int k0 = 0; k0 < K; k0 += 32) {
    __syncthreads();
    gload16(gA0 + k0, &sAh[tid * 8]);
    gload16(gA1 + k0, &sAh[2048 + tid * 8]);
    gload16(gB0 + k0, &sBh[tid * 8]);
    gload16(gB1 + k0, &sBh[2048 + tid * 8]);
    if constexpr (SPLIT) {
      gload16(gA0l + k0, &sAl[tid * 8]);
      gload16(gA1l + k0, &sAl[2048 + tid * 8]);
      gload16(gB0l + k0, &sBl[tid * 8]);
      gload16(gB1l + k0, &sBl[2048 + tid * 8]);
    }
    __syncthreads();

    bf16x8 af[4], bfv[4];
#pragma unroll
    for (int i = 0; i < 4; i++)
      af[i] = *(const bf16x8*)&sAh[(wm + i * 16 + lr) * 32 + kg * 8];
#pragma unroll
    for (int i = 0; i < 4; i++)
      bfv[i] = *(const bf16x8*)&sBh[(wn + i * 16 + lr) * 32 + kg * 8];

#pragma unroll
    for (int mi = 0; mi < 4; mi++)
#pragma unroll
      for (int ni = 0; ni < 4; ni++)
        acc[mi][ni] = __builtin_amdgcn_mfma_f32_16x16x32_bf16(
            af[mi], bfv[ni], acc[mi][ni], 0, 0, 0);

    if constexpr (SPLIT) {
      bf16x8 afl[4], bfl[4];
#pragma unroll
      for (int i = 0; i < 4; i++)
        afl[i] = *(const bf16x8*)&sAl[(wm + i * 16 + lr) * 32 + kg * 8];
#pragma unroll
      for (int i = 0; i < 4; i++)
        bfl[i] = *(const bf16x8*)&sBl[(wn + i * 16 + lr) * 32 + kg * 8];
#pragma unroll
      for (int mi = 0; mi < 4; mi++)
#pragma unroll
        for (int ni = 0; ni < 4; ni++) {
          acc[mi][ni] = __builtin_amdgcn_mfma_f32_16x16x32_bf16(
              afl[mi], bfv[ni], acc[mi][ni], 0, 0, 0);
          acc[mi][ni] = __builtin_amdgcn_mfma_f32_16x16x32_bf16(
              af[mi], bfl[ni], acc[mi][ni], 0, 0, 0);
        }
    }
  }

#pragma unroll
  for (int mi = 0; mi < 4; mi++) {
#pragma unroll
    for (int ni = 0; ni < 4; ni++) {
      const int col = bn + wn + ni * 16 + lr;
      float bv = 0.f;
      if constexpr (BIAS) bv = bias[col];
#pragma unroll
      for (int r = 0; r < 4; r++) {
        const int row = bm + wm + mi * 16 + kg * 4 + r;
        C[(size_t)row * N + col] = acc[mi][ni][r] + bv;
      }
    }
  }
}

// ========== 256x256 8-wave deep-pipelined GEMM (T1+T2+T3+T4+T5) =============
// C(MxN) = A(MxK) * Bt(NxK)^T + bias.  BK=32, 4-deep LDS ring (128 KiB dyn).
// Ring safety: stage(t+3) lands in buf[(t+3)&3] = buf[(t-1)&3]; all reads of
// tile t-1 finished before the boundary barrier that precedes this body.
// Counted vmcnt(8) at tile boundary: waits until only t+2,t+3 loads remain,
// i.e. tile t+1 fully landed (per-wave), then s_barrier makes it global.
// LDS swizzle: 16B-slot' = slot ^ ((row>>1)&3); gload_lds dest stays linear,
// the global SOURCE is inverse-permuted; ds_read applies the same XOR.
// (round-3 bug fixed: boff had the +8192 B-region offset double-counted with
//  lB = lA + 8192 -> OOB LDS reads on buf3 -> NaN)
__global__ __launch_bounds__(512, 2) void k_gemm8(
    const bf16* __restrict__ A, const bf16* __restrict__ Bt,
    const float* __restrict__ bias, float* __restrict__ C,
    int M, int N, int K, int mblocks) {
  extern __shared__ bf16 lds[];   // [4 bufs][A 8192 el | B 8192 el]

  // T1: bijective XCD swizzle (gridDim.x % 8 == 0 guaranteed by host)
  const int orig = (blockIdx.x & 7) * ((int)gridDim.x >> 3) + (blockIdx.x >> 3);
  const int bm = (orig % mblocks) * 256;
  const int bn = (orig / mblocks) * 256;

  const int tid  = threadIdx.x;
  const int lane = tid & 63;
  const int wave = tid >> 6;       // 0..7
  const int wm   = wave >> 2;      // 0..1 : M half (128 rows)
  const int wn   = wave & 3;       // 0..3 : N quarter (64 cols)
  const int lr   = lane & 15;
  const int kg   = lane >> 4;      // 0..3 : 16B k-slot
  const int sw   = (lr >> 1) & 3;  // read-side swizzle key

  // staging: wave w covers rows [32w, 32w+32) of the 256x32 tile (2 insts)
  const int srow  = (wave << 5) + (lane >> 2);
  const int sslot = (lane & 3) ^ ((srow >> 1) & 3);         // inverse-permuted source slot
  const size_t gAoff = (size_t)(bm + srow) * K + sslot * 8;
  const size_t gBoff = (size_t)(bn + srow) * K + sslot * 8;
  const int ldsoff = tid * 8 + wave * 512;                  // linear dest (elements)

  // fragment read offsets within a buffer (elements, swizzled)
  const int aoff = (wm * 128 + lr) * 32 + ((kg ^ sw) << 3);
  const int boff = (wn * 64 + lr) * 32 + ((kg ^ sw) << 3);   // NOTE: no +8192; lB carries it

  const int nt = K >> 5;   // K/32 tiles; callers have nt >= 4

#define STAGE8(ts_) do {                                                   \
    bf16* lb_ = lds + ((ts_) & 3) * 16384;                                 \
    const size_t ko_ = (size_t)(ts_) * 32;                                 \
    gload16(A  + gAoff + ko_,            lb_ + ldsoff);                    \
    gload16(A  + gAoff + 16 * (size_t)K + ko_, lb_ + ldsoff + 512);        \
    gload16(Bt + gBoff + ko_,            lb_ + 8192 + ldsoff);             \
    gload16(Bt + gBoff + 16 * (size_t)K + ko_, lb_ + 8192 + ldsoff + 512); \
  } while (0)

  f32x4 acc[8][4] = {};

  // prologue: tiles 0,1,2 in flight; wait for tile 0 (8 = loads of t1,t2)
  STAGE8(0); STAGE8(1); STAGE8(2);
  asm volatile("s_waitcnt vmcnt(8)" ::: "memory");
  __builtin_amdgcn_s_barrier();
  asm volatile("" ::: "memory");

  for (int t = 0; t < nt; ++t) {
    if (t + 3 < nt) STAGE8(t + 3);   // issue prefetch BEFORE ds_read/MFMA

    const bf16* lA = lds + (t & 3) * 16384;
    const bf16* lB = lA + 8192;

    bf16x8 bfr[4];
#pragma unroll
    for (int j = 0; j < 4; j++) bfr[j] = *(const bf16x8*)(lB + boff + j * 512);
    bf16x8 afr[4];
#pragma unroll
    for (int i = 0; i < 4; i++) afr[i] = *(const bf16x8*)(lA + aoff + i * 512);

    __builtin_amdgcn_s_setprio(1);
#pragma unroll
    for (int i = 0; i < 4; i++)
#pragma unroll
      for (int j = 0; j < 4; j++)
        acc[i][j] = __builtin_amdgcn_mfma_f32_16x16x32_bf16(afr[i], bfr[j], acc[i][j], 0, 0, 0);
    __builtin_amdgcn_s_setprio(0);

#pragma unroll
    for (int i = 0; i < 4; i++) afr[i] = *(const bf16x8*)(lA + aoff + (i + 4) * 512);

    __builtin_amdgcn_s_setprio(1);
#pragma unroll
    for (int i = 0; i < 4; i++)
#pragma unroll
      for (int j = 0; j < 4; j++)
        acc[i + 4][j] = __builtin_amdgcn_mfma_f32_16x16x32_bf16(afr[i], bfr[j], acc[i + 4][j], 0, 0, 0);
    __builtin_amdgcn_s_setprio(0);

    // boundary: tile t+1 must be landed globally before next iteration reads
    if (t + 4 <= nt)      { asm volatile("s_waitcnt vmcnt(8)" ::: "memory"); }
    else if (t + 3 == nt) { asm volatile("s_waitcnt vmcnt(4)" ::: "memory"); }
    else if (t + 2 == nt) { asm volatile("s_waitcnt vmcnt(0)" ::: "memory"); }
    if (t + 1 < nt) {
      __builtin_amdgcn_s_barrier();
      asm volatile("" ::: "memory");
    }
  }
#undef STAGE8

  // epilogue: C/D layout col=lane&15, row=(lane>>4)*4+r
  float bv[4];
#pragma unroll
  for (int j = 0; j < 4; j++)
    bv[j] = bias ? bias[bn + wn * 64 + j * 16 + lr] : 0.f;
#pragma unroll
  for (int i = 0; i < 8; i++) {
    const int row = bm + wm * 128 + i * 16 + kg * 4;
#pragma unroll
    for (int j = 0; j < 4; j++) {
      const int col = bn + wn * 64 + j * 16 + lr;
#pragma unroll
      for (int r = 0; r < 4; r++)
        C[(size_t)(row + r) * N + col] = acc[i][j][r] + bv[j];
    }
  }
}

// ---------------- depthwise causal conv (D_CONV=4) + silu -------------------
__global__ void k_conv(const float* __restrict__ xz, const float* __restrict__ cw,
                       const float* __restrict__ cb, float* __restrict__ xa) {
  const int bl = blockIdx.x;
  const int l  = bl & (L_SEQ - 1);
  for (int d = threadIdx.x; d < DINNER; d += blockDim.x) {
    float acc = cb[d];
#pragma unroll
    for (int k = 0; k < 4; k++) {
      const int ll = l + k - 3;
      if (ll >= 0)
        acc = fmaf(xz[(size_t)(bl + k - 3) * (2 * DINNER) + d], cw[d * 4 + k], acc);
    }
    xa[(size_t)bl * DINNER + d] = acc / (1.f + __expf(-acc));
  }
}

// ---------------- x_proj: dbl(2048,80) = xa(2048,1536) @ w(1536,80), fp32 ---
__global__ void k_xproj(const float* __restrict__ xa, const float* __restrict__ w,
                        float* __restrict__ dbl) {
  const int t = threadIdx.x;               // 640 = 8 rows x 80 cols
  const int r = blockIdx.x * 8 + t / 80;
  const int c = t % 80;
  const float* xr = xa + (size_t)r * DINNER;
  float acc = 0.f;
  for (int k = 0; k < DINNER; k++) acc = fmaf(xr[k], w[k * 80 + c], acc);
  dbl[(size_t)r * 80 + c] = acc;
}

// ---------------- dt_proj + softplus, fp32 ----------------------------------
__global__ void k_dtproj(const float* __restrict__ dbl, const float* __restrict__ w,
                         const float* __restrict__ bvec, float* __restrict__ dt) {
  const int r = blockIdx.x;
  __shared__ float ds[DTRANK];
  if (threadIdx.x < DTRANK) ds[threadIdx.x] = dbl[(size_t)r * 80 + threadIdx.x];
  __syncthreads();
  for (int c = threadIdx.x; c < DINNER; c += blockDim.x) {
    float acc = bvec[c];
#pragma unroll
    for (int k = 0; k < DTRANK; k++) acc = fmaf(ds[k], w[k * DINNER + c], acc);
    dt[(size_t)r * DINNER + c] = (acc > 20.f) ? acc : log1pf(expf(acc));
  }
}

// ======================= chunk-parallel selective scan =======================
__global__ __launch_bounds__(256) void k_scan1(
    const float* __restrict__ dt, const float* __restrict__ dbl,
    const float* __restrict__ xa, const float* __restrict__ a_log,
    float* __restrict__ P, float* __restrict__ S) {
  const int tid = threadIdx.x;
  const int d = blockIdx.x * 256 + tid;
  const int c = blockIdx.y;
  const int b = blockIdx.z;
  __shared__ float sB[CLEN][DSTATE];
  {
    const int j = tid >> 4, n = tid & 15;
    sB[j][n] = dbl[(size_t)(b * L_SEQ + c * CLEN + j) * 80 + DTRANK + n];
  }
  __syncthreads();
  float a[16];
#pragma unroll
  for (int q = 0; q < 4; q++) {
    const float4 v = *(const float4*)&a_log[d * DSTATE + q * 4];
    a[q*4+0] = -expf(v.x); a[q*4+1] = -expf(v.y);
    a[q*4+2] = -expf(v.z); a[q*4+3] = -expf(v.w);
  }
  float h[16] = {}, p[16];
#pragma unroll
  for (int n = 0; n < 16; n++) p[n] = 1.f;
  const size_t rowb = (size_t)(b * L_SEQ + c * CLEN);
#pragma unroll 4
  for (int j = 0; j < CLEN; j++) {
    const size_t row = rowb + j;
    const float dtv = dt[row * DINNER + d];
    const float xav = xa[row * DINNER + d];
    const float du  = dtv * xav;
#pragma unroll
    for (int n = 0; n < 16; n++) {
      const float dA = __expf(dtv * a[n]);
      h[n] = fmaf(dA, h[n], du * sB[j][n]);
      p[n] *= dA;
    }
  }
  const size_t base = (((size_t)c * B_SZ + b) * DINNER + d) * DSTATE;
#pragma unroll
  for (int q = 0; q < 4; q++) {
    *(float4*)&P[base + q * 4] = make_float4(p[q*4], p[q*4+1], p[q*4+2], p[q*4+3]);
    *(float4*)&S[base + q * 4] = make_float4(h[q*4], h[q*4+1], h[q*4+2], h[q*4+3]);
  }
}

__global__ __launch_bounds__(256) void k_scan2(
    const float* __restrict__ P, const float* __restrict__ S,
    float* __restrict__ Hin) {
  const int gid = blockIdx.x * 256 + threadIdx.x;   // (b*DINNER+d)*16+n
  const int STRIDE = B_SZ * DINNER * DSTATE;        // 49152
  float h = 0.f;
#pragma unroll 4
  for (int c = 0; c < NCH; c++) {
    Hin[(size_t)c * STRIDE + gid] = h;
    h = fmaf(P[(size_t)c * STRIDE + gid], h, S[(size_t)c * STRIDE + gid]);
  }
}

__global__ __launch_bounds__(256) void k_scan3(
    const float* __restrict__ dt, const float* __restrict__ dbl,
    const float* __restrict__ xa, const float* __restrict__ a_log,
    const float* __restrict__ dvec, const float* __restrict__ xz,
    const float* __restrict__ Hin, float* __restrict__ ycmb) {
  const int tid = threadIdx.x;
  const int d = blockIdx.x * 256 + tid;
  const int c = blockIdx.y;
  const int b = blockIdx.z;
  __shared__ float sB[CLEN][DSTATE];
  __shared__ float sC[CLEN][DSTATE];
  {
    const int j = tid >> 4, n = tid & 15;
    const size_t r80 = (size_t)(b * L_SEQ + c * CLEN + j) * 80;
    sB[j][n] = dbl[r80 + DTRANK + n];
    sC[j][n] = dbl[r80 + DTRANK + DSTATE + n];
  }
  __syncthreads();
  float a[16];
#pragma unroll
  for (int q = 0; q < 4; q++) {
    const float4 v = *(const float4*)&a_log[d * DSTATE + q * 4];
    a[q*4+0] = -expf(v.x); a[q*4+1] = -expf(v.y);
    a[q*4+2] = -expf(v.z); a[q*4+3] = -expf(v.w);
  }
  float h[16];
  const size_t base = (((size_t)c * B_SZ + b) * DINNER + d) * DSTATE;
#pragma unroll
  for (int q = 0; q < 4; q++) {
    const float4 v = *(const float4*)&Hin[base + q * 4];
    h[q*4+0] = v.x; h[q*4+1] = v.y; h[q*4+2] = v.z; h[q*4+3] = v.w;
  }
  const float Dv = dvec[d];
  const size_t rowb = (size_t)(b * L_SEQ + c * CLEN);
#pragma unroll 4
  for (int j = 0; j < CLEN; j++) {
    const size_t row = rowb + j;
    const float dtv = dt[row * DINNER + d];
    const float xav = xa[row * DINNER + d];
    const float du  = dtv * xav;
    float y = 0.f;
#pragma unroll
    for (int n = 0; n < 16; n++) {
      const float dA = __expf(dtv * a[n]);
      h[n] = fmaf(dA, h[n], du * sB[j][n]);
      y = fmaf(h[n], sC[j][n], y);
    }
    const float z  = xz[row * (2 * DINNER) + DINNER + d];
    const float sz = z / (1.f + __expf(-z));
    ycmb[row * DINNER + d] = fmaf(xav, Dv, y) * sz;
  }
}

// ============================================================================
extern "C" void kernel_launch(void* const* d_in, const int* in_sizes, int n_in,
                              void* d_out, int out_size, void* d_ws, size_t ws_size,
                              hipStream_t stream) {
  const int*   ids   = (const int*)d_in[0];
  const float* emb   = (const float*)d_in[1];
  const float* w_in  = (const float*)d_in[2];   // 768 x 3072
  const float* cw    = (const float*)d_in[3];   // 1536 x 4
  const float* cb    = (const float*)d_in[4];
  const float* w_x   = (const float*)d_in[5];   // 1536 x 80
  const float* w_dt  = (const float*)d_in[6];   // 48 x 1536
  const float* b_dt  = (const float*)d_in[7];
  const float* a_log = (const float*)d_in[8];   // 1536 x 16
  const float* dvec  = (const float*)d_in[9];
  const float* w_out = (const float*)d_in[10];  // 1536 x 768
  const float* w_lm  = (const float*)d_in[11];  // 768 x 32000
  const float* b_lm  = (const float*)d_in[12];
  float* out = (float*)d_out;

  char* ws = (char*)d_ws;
  size_t off = 0;
  auto alloc = [&](size_t bytes) {
    void* p = ws + off;
    off = (off + bytes + 255) & ~(size_t)255;
    return p;
  };
  float* xw    = (float*)alloc((size_t)BL * DMODEL * 4);
  float* xz    = (float*)alloc((size_t)BL * 2 * DINNER * 4);
  float* xa    = (float*)alloc((size_t)BL * DINNER * 4);
  float* dbl   = (float*)alloc((size_t)BL * 80 * 4);
  float* dt    = (float*)alloc((size_t)BL * DINNER * 4);
  float* ycmb  = (float*)alloc((size_t)BL * DINNER * 4);
  float* yo    = (float*)alloc((size_t)BL * DMODEL * 4);
  bf16* xwh    = (bf16*)alloc((size_t)BL * DMODEL * 2);
  bf16* xwl    = (bf16*)alloc((size_t)BL * DMODEL * 2);
  bf16* wtinh  = (bf16*)alloc((size_t)3072 * DMODEL * 2);
  bf16* wtinl  = (bf16*)alloc((size_t)3072 * DMODEL * 2);
  bf16* ych    = (bf16*)alloc((size_t)BL * DINNER * 2);
  bf16* ycl    = (bf16*)alloc((size_t)BL * DINNER * 2);
  bf16* wtoh   = (bf16*)alloc((size_t)DMODEL * DINNER * 2);
  bf16* wtol   = (bf16*)alloc((size_t)DMODEL * DINNER * 2);
  bf16* yob    = (bf16*)alloc((size_t)BL * DMODEL * 2);
  bf16* wtlm   = (bf16*)alloc((size_t)VOCAB * DMODEL * 2);
  if (off > ws_size) {
    fprintf(stderr, "kernel_launch: ws too small (need %zu, have %zu)\n", off, ws_size);
    return;
  }

  // Scan scratch aliased onto dead-lifetime regions (see round-1 notes)
  float* Pbuf = (float*)xwh;
  float* Sbuf = (float*)ych;
  float* Hin  = (float*)wtlm;

  // allow 128 KiB dynamic LDS for k_gemm8 (capture-safe: no enqueue)
  (void)hipFuncSetAttribute((const void*)k_gemm8,
                            hipFuncAttributeMaxDynamicSharedMemorySize, 131072);

  // 1. embed
  k_embed<<<BL, 192, 0, stream>>>(ids, emb, xw);
  // 2. split activations + transpose-convert in_proj weight
  k_split4<<<(BL * DMODEL / 4 + 255) / 256, 256, 0, stream>>>(xw, xwh, xwl, BL * DMODEL / 4);
  k_tconv<true><<<dim3(3072 / 32, DMODEL / 32), dim3(32, 8), 0, stream>>>(w_in, wtinh, wtinl, DMODEL, 3072);
  // 3. in_proj GEMM (split, fp32-exact-ish): xz = xw @ w_in
  k_gemm<true, false><<<dim3(3072 / 128, BL / 128), 256, 0, stream>>>(
      xwh, xwl, wtinh, wtinl, nullptr, xz, BL, 3072, DMODEL);
  // 4. conv + silu
  k_conv<<<BL, 256, 0, stream>>>(xz, cw, cb, xa);
  // 5. x_proj (fp32)
  k_xproj<<<BL / 8, 640, 0, stream>>>(xa, w_x, dbl);
  // 6. dt_proj + softplus (fp32)
  k_dtproj<<<BL, 256, 0, stream>>>(dbl, w_dt, b_dt, dt);
  // 7. chunk-parallel scan + fused combine epilogue (fp32)
  k_scan1<<<dim3(DINNER / 256, NCH, B_SZ), 256, 0, stream>>>(dt, dbl, xa, a_log, Pbuf, Sbuf);
  k_scan2<<<(B_SZ * DINNER * DSTATE) / 256, 256, 0, stream>>>(Pbuf, Sbuf, Hin);
  k_scan3<<<dim3(DINNER / 256, NCH, B_SZ), 256, 0, stream>>>(dt, dbl, xa, a_log, dvec, xz, Hin, ycmb);
  // 8. out_proj GEMM (split): yo = ycmb @ w_out
  k_split4<<<(BL * DINNER / 4 + 255) / 256, 256, 0, stream>>>(ycmb, ych, ycl, BL * DINNER / 4);
  k_tconv<true><<<dim3(DMODEL / 32, DINNER / 32), dim3(32, 8), 0, stream>>>(w_out, wtoh, wtol, DINNER, DMODEL);
  k_gemm<true, false><<<dim3(DMODEL / 128, BL / 128), 256, 0, stream>>>(
      ych, ycl, wtoh, wtol, nullptr, yo, BL, DMODEL, DINNER);
  // 9. lm_head GEMM: 256x256 8-wave deep-pipelined, bf16 + fp32 bias
  k_cvt4<<<(BL * DMODEL / 4 + 255) / 256, 256, 0, stream>>>(yo, yob, BL * DMODEL / 4);
  k_tconv<false><<<dim3(VOCAB / 32, DMODEL / 32), dim3(32, 8), 0, stream>>>(w_lm, wtlm, nullptr, DMODEL, VOCAB);
  {
    const int mb = BL / 256;                 // 8
    const int nb = VOCAB / 256;              // 125
    k_gemm8<<<mb * nb, 512, 131072, stream>>>(yob, wtlm, b_lm, out,
                                              BL, VOCAB, DMODEL, mb);
  }
}

// Round 5
// 570.088 us; speedup vs baseline: 2.2648x; 1.0016x over previous
//
#include <hip/hip_runtime.h>
#include <hip/hip_bf16.h>
#include <cstdio>
#include <cstdint>

#define B_SZ    2
#define L_SEQ   1024
#define DMODEL  768
#define DINNER  1536
#define DSTATE  16
#define DTRANK  48
#define VOCAB   32000
#define BL      (B_SZ * L_SEQ)   // 2048
#define NCH     64               // scan chunks per sequence
#define CLEN    16               // timesteps per chunk (NCH*CLEN == L_SEQ)

typedef __bf16 bf16;
typedef __bf16 bf16x8 __attribute__((ext_vector_type(8)));
typedef __bf16 bf16x4 __attribute__((ext_vector_type(4)));
typedef float  f32x4  __attribute__((ext_vector_type(4)));

// ---------------- async global->LDS (16B/lane, wave-uniform base + lane*16) --
__device__ __forceinline__ void gload16(const void* g, void* l) {
  __builtin_amdgcn_global_load_lds(
      (const __attribute__((address_space(1))) void*)g,
      (__attribute__((address_space(3))) void*)l, 16, 0, 0);
}
__device__ __forceinline__ void memfence() { asm volatile("" ::: "memory"); }

// ---------------- embedding gather ------------------------------------------
__global__ void k_embed(const int* __restrict__ ids, const float* __restrict__ emb,
                        float* __restrict__ xw) {
  const int row = blockIdx.x;
  const int id  = ids[row];
  const float4* s = (const float4*)(emb + (size_t)id * DMODEL);
  float4* d = (float4*)(xw + (size_t)row * DMODEL);
  for (int i = threadIdx.x; i < DMODEL / 4; i += blockDim.x) d[i] = s[i];
}

// ---------------- f32 -> bf16 hi/lo split (activations) ---------------------
__global__ void k_split4(const float* __restrict__ x, bf16* __restrict__ h,
                         bf16* __restrict__ l, int n4) {
  const int i = blockIdx.x * blockDim.x + threadIdx.x;
  if (i >= n4) return;
  const float4 v = ((const float4*)x)[i];
  bf16x4 hv, lv;
  hv[0] = (bf16)v.x; hv[1] = (bf16)v.y; hv[2] = (bf16)v.z; hv[3] = (bf16)v.w;
  lv[0] = (bf16)(v.x - (float)hv[0]); lv[1] = (bf16)(v.y - (float)hv[1]);
  lv[2] = (bf16)(v.z - (float)hv[2]); lv[3] = (bf16)(v.w - (float)hv[3]);
  *(bf16x4*)(h + (size_t)i * 4) = hv;
  *(bf16x4*)(l + (size_t)i * 4) = lv;
}

__global__ void k_cvt4(const float* __restrict__ x, bf16* __restrict__ h, int n4) {
  const int i = blockIdx.x * blockDim.x + threadIdx.x;
  if (i >= n4) return;
  const float4 v = ((const float4*)x)[i];
  bf16x4 hv;
  hv[0] = (bf16)v.x; hv[1] = (bf16)v.y; hv[2] = (bf16)v.z; hv[3] = (bf16)v.w;
  *(bf16x4*)(h + (size_t)i * 4) = hv;
}

// ---------------- weight transpose + convert: W(K,N) f32 -> WT(N,K) bf16 ----
template<bool SPLIT>
__global__ void k_tconv(const float* __restrict__ W, bf16* __restrict__ Th,
                        bf16* __restrict__ Tl, int K, int N) {
  __shared__ float t[32][33];
  const int n0 = blockIdx.x * 32;
  const int k0 = blockIdx.y * 32;
  const int tx = threadIdx.x;   // 0..31
  const int ty = threadIdx.y;   // 0..7
#pragma unroll
  for (int i = 0; i < 4; i++)
    t[ty + i * 8][tx] = W[(size_t)(k0 + ty + i * 8) * N + n0 + tx];
  __syncthreads();
#pragma unroll
  for (int i = 0; i < 4; i++) {
    const float v = t[tx][ty + i * 8];
    const bf16 hv = (bf16)v;
    Th[(size_t)(n0 + ty + i * 8) * K + k0 + tx] = hv;
    if constexpr (SPLIT)
      Tl[(size_t)(n0 + ty + i * 8) * K + k0 + tx] = (bf16)(v - (float)hv);
  }
}

// ---------------- bf16 MFMA GEMM, 128x128, double-buffered 2-phase ----------
// minimum-2-phase: stage(t+1) issued BEFORE compute(t); one vmcnt(0)+barrier
// per K-tile (catalog T3-minimum). SPLIT: AhBh + AlBh + AhBl.
template<bool SPLIT, bool BIAS>
__global__ __launch_bounds__(256) void k_gemm(
    const bf16* __restrict__ Ah, const bf16* __restrict__ Al,
    const bf16* __restrict__ Bh, const bf16* __restrict__ Bl,
    const float* __restrict__ bias, float* __restrict__ C,
    int M, int N, int K) {
  __shared__ bf16 sAh[2][128 * 32];
  __shared__ bf16 sBh[2][128 * 32];
  __shared__ bf16 sAl[SPLIT ? 2 : 1][SPLIT ? 128 * 32 : 8];
  __shared__ bf16 sBl[SPLIT ? 2 : 1][SPLIT ? 128 * 32 : 8];

  const int tid  = threadIdx.x;
  const int lane = tid & 63;
  const int wave = tid >> 6;
  const int bm = blockIdx.y * 128;
  const int bn = blockIdx.x * 128;

  const int srow = tid >> 2;         // 0..63: staging row
  const int schk = (tid & 3) * 8;    // element offset in 32-wide K slab

  const bf16* gA0 = Ah + (size_t)(bm + srow) * K + schk;
  const bf16* gA1 = gA0 + (size_t)64 * K;
  const bf16* gB0 = Bh + (size_t)(bn + srow) * K + schk;
  const bf16* gB1 = gB0 + (size_t)64 * K;
  const bf16 *gA0l = nullptr, *gA1l = nullptr, *gB0l = nullptr, *gB1l = nullptr;
  if constexpr (SPLIT) {
    gA0l = Al + (size_t)(bm + srow) * K + schk;  gA1l = gA0l + (size_t)64 * K;
    gB0l = Bl + (size_t)(bn + srow) * K + schk;  gB1l = gB0l + (size_t)64 * K;
  }

  const int wm = (wave >> 1) * 64;
  const int wn = (wave & 1) * 64;
  const int lr = lane & 15;
  const int kg = lane >> 4;

  f32x4 acc[4][4] = {};
  const int nt = K >> 5;

#define STG(t_, b_) do {                                                    \
    const size_t ko_ = (size_t)(t_) * 32;                                   \
    gload16(gA0 + ko_, &sAh[b_][tid * 8]);                                  \
    gload16(gA1 + ko_, &sAh[b_][2048 + tid * 8]);                           \
    gload16(gB0 + ko_, &sBh[b_][tid * 8]);                                  \
    gload16(gB1 + ko_, &sBh[b_][2048 + tid * 8]);                           \
    if constexpr (SPLIT) {                                                  \
      gload16(gA0l + ko_, &sAl[b_][tid * 8]);                               \
      gload16(gA1l + ko_, &sAl[b_][2048 + tid * 8]);                        \
      gload16(gB0l + ko_, &sBl[b_][tid * 8]);                               \
      gload16(gB1l + ko_, &sBl[b_][2048 + tid * 8]);                        \
    }                                                                       \
  } while (0)

  STG(0, 0);
  asm volatile("s_waitcnt vmcnt(0)" ::: "memory");
  __builtin_amdgcn_s_barrier();
  memfence();

  for (int t = 0; t < nt; ++t) {
    const int b = t & 1;
    if (t + 1 < nt) STG(t + 1, b ^ 1);   // overlap next-tile staging w/ compute

    bf16x8 af[4], bfv[4];
#pragma unroll
    for (int i = 0; i < 4; i++)
      af[i] = *(const bf16x8*)&sAh[b][(wm + i * 16 + lr) * 32 + kg * 8];
#pragma unroll
    for (int i = 0; i < 4; i++)
      bfv[i] = *(const bf16x8*)&sBh[b][(wn + i * 16 + lr) * 32 + kg * 8];

#pragma unroll
    for (int mi = 0; mi < 4; mi++)
#pragma unroll
      for (int ni = 0; ni < 4; ni++)
        acc[mi][ni] = __builtin_amdgcn_mfma_f32_16x16x32_bf16(
            af[mi], bfv[ni], acc[mi][ni], 0, 0, 0);

    if constexpr (SPLIT) {
      bf16x8 afl[4], bfl[4];
#pragma unroll
      for (int i = 0; i < 4; i++)
        afl[i] = *(const bf16x8*)&sAl[b][(wm + i * 16 + lr) * 32 + kg * 8];
#pragma unroll
      for (int i = 0; i < 4; i++)
        bfl[i] = *(const bf16x8*)&sBl[b][(wn + i * 16 + lr) * 32 + kg * 8];
#pragma unroll
      for (int mi = 0; mi < 4; mi++)
#pragma unroll
        for (int ni = 0; ni < 4; ni++) {
          acc[mi][ni] = __builtin_amdgcn_mfma_f32_16x16x32_bf16(
              afl[mi], bfv[ni], acc[mi][ni], 0, 0, 0);
          acc[mi][ni] = __builtin_amdgcn_mfma_f32_16x16x32_bf16(
              af[mi], bfl[ni], acc[mi][ni], 0, 0, 0);
        }
    }

    asm volatile("s_waitcnt vmcnt(0)" ::: "memory");  // next tile landed
    __builtin_amdgcn_s_barrier();                     // all waves done w/ buf b
    memfence();
  }
#undef STG

#pragma unroll
  for (int mi = 0; mi < 4; mi++) {
#pragma unroll
    for (int ni = 0; ni < 4; ni++) {
      const int col = bn + wn + ni * 16 + lr;
      float bv = 0.f;
      if constexpr (BIAS) bv = bias[col];
#pragma unroll
      for (int r = 0; r < 4; r++) {
        const int row = bm + wm + mi * 16 + kg * 4 + r;
        C[(size_t)row * N + col] = acc[mi][ni][r] + bv;
      }
    }
  }
}

// ========== 256x256 8-wave deep-pipelined GEMM (T1+T2+T3+T4+T5) =============
// C(MxN) = A(MxK) * Bt(NxK)^T + bias.  BK=32, 4-deep LDS ring (128 KiB dyn).
// Round-5: m201-style fine phases. Per K-tile, 2 phases of 16 MFMA each:
//   ph0: ds_read B(4)+A-lo(4); issue stage-A(t+3); BAR; MFMA x16; BAR
//   ph1: ds_read A-hi(4);      issue stage-B(t+3); BAR; MFMA x16;
//        counted vmcnt (never 0 mid-loop); BAR
// Ring safety: stage(t+3) -> buf[(t-1)&3], whose readers finished in iter t-1.
// vmcnt(8): waits until only t+2/t+3's 8 loads outstanding => t+1 landed.
__global__ __launch_bounds__(512, 2) void k_gemm8(
    const bf16* __restrict__ A, const bf16* __restrict__ Bt,
    const float* __restrict__ bias, float* __restrict__ C,
    int M, int N, int K, int mblocks) {
  extern __shared__ bf16 lds[];   // [4 bufs][A 8192 el | B 8192 el]

  // T1: bijective XCD swizzle (gridDim.x % 8 == 0 guaranteed by host)
  const int orig = (blockIdx.x & 7) * ((int)gridDim.x >> 3) + (blockIdx.x >> 3);
  const int bm = (orig % mblocks) * 256;
  const int bn = (orig / mblocks) * 256;

  const int tid  = threadIdx.x;
  const int lane = tid & 63;
  const int wave = tid >> 6;       // 0..7
  const int wm   = wave >> 2;      // 0..1 : M half (128 rows)
  const int wn   = wave & 3;       // 0..3 : N quarter (64 cols)
  const int lr   = lane & 15;
  const int kg   = lane >> 4;      // 0..3 : 16B k-slot
  const int sw   = (lr >> 1) & 3;  // read-side swizzle key

  // staging: wave w covers rows [32w, 32w+32) of the 256x32 tile (2 insts)
  const int srow  = (wave << 5) + (lane >> 2);
  const int sslot = (lane & 3) ^ ((srow >> 1) & 3);         // inverse-permuted source slot
  const size_t gAoff = (size_t)(bm + srow) * K + sslot * 8;
  const size_t gBoff = (size_t)(bn + srow) * K + sslot * 8;
  const int ldsoff = tid * 8 + wave * 512;                  // linear dest (elements)

  // fragment read offsets within a buffer (elements, swizzled)
  const int aoff = (wm * 128 + lr) * 32 + ((kg ^ sw) << 3);
  const int boff = (wn * 64 + lr) * 32 + ((kg ^ sw) << 3);

  const int nt = K >> 5;   // K/32 tiles; callers have nt >= 4

#define STAGE_A(ts_) do {                                                  \
    bf16* lb_ = lds + ((ts_) & 3) * 16384;                                 \
    const size_t ko_ = (size_t)(ts_) * 32;                                 \
    gload16(A + gAoff + ko_,                 lb_ + ldsoff);                \
    gload16(A + gAoff + 16 * (size_t)K + ko_, lb_ + ldsoff + 512);         \
  } while (0)
#define STAGE_B(ts_) do {                                                  \
    bf16* lb_ = lds + ((ts_) & 3) * 16384;                                 \
    const size_t ko_ = (size_t)(ts_) * 32;                                 \
    gload16(Bt + gBoff + ko_,                 lb_ + 8192 + ldsoff);        \
    gload16(Bt + gBoff + 16 * (size_t)K + ko_, lb_ + 8192 + ldsoff + 512); \
  } while (0)

  f32x4 acc[8][4] = {};

  // prologue: tiles 0,1,2 in flight; wait tile 0 (8 = loads of t1,t2)
  STAGE_A(0); STAGE_B(0);
  STAGE_A(1); STAGE_B(1);
  STAGE_A(2); STAGE_B(2);
  asm volatile("s_waitcnt vmcnt(8)" ::: "memory");
  __builtin_amdgcn_s_barrier();
  memfence();

  for (int t = 0; t < nt; ++t) {
    const bf16* lA = lds + (t & 3) * 16384;
    const bf16* lB = lA + 8192;

    // ----- phase 0: B(4) + A-lo(4) reads, stage A(t+3), MFMA lower half -----
    bf16x8 bfr[4], afr[4];
#pragma unroll
    for (int j = 0; j < 4; j++) bfr[j] = *(const bf16x8*)(lB + boff + j * 512);
#pragma unroll
    for (int i = 0; i < 4; i++) afr[i] = *(const bf16x8*)(lA + aoff + i * 512);
    if (t + 3 < nt) STAGE_A(t + 3);
    memfence();
    __builtin_amdgcn_s_barrier();
    memfence();

    __builtin_amdgcn_s_setprio(1);
#pragma unroll
    for (int i = 0; i < 4; i++)
#pragma unroll
      for (int j = 0; j < 4; j++)
        acc[i][j] = __builtin_amdgcn_mfma_f32_16x16x32_bf16(afr[i], bfr[j], acc[i][j], 0, 0, 0);
    __builtin_amdgcn_s_setprio(0);
    memfence();
    __builtin_amdgcn_s_barrier();
    memfence();

    // ----- phase 1: A-hi(4) reads, stage B(t+3), MFMA upper half ------------
    bf16x8 af2[4];
#pragma unroll
    for (int i = 0; i < 4; i++) af2[i] = *(const bf16x8*)(lA + aoff + (i + 4) * 512);
    if (t + 3 < nt) STAGE_B(t + 3);
    memfence();
    __builtin_amdgcn_s_barrier();
    memfence();

    __builtin_amdgcn_s_setprio(1);
#pragma unroll
    for (int i = 0; i < 4; i++)
#pragma unroll
      for (int j = 0; j < 4; j++)
        acc[i + 4][j] = __builtin_amdgcn_mfma_f32_16x16x32_bf16(af2[i], bfr[j], acc[i + 4][j], 0, 0, 0);
    __builtin_amdgcn_s_setprio(0);

    // counted wait: tile t+1 fully landed before next iter's ds_reads
    if (t + 4 <= nt)      { asm volatile("s_waitcnt vmcnt(8)" ::: "memory"); }
    else if (t + 3 == nt) { asm volatile("s_waitcnt vmcnt(4)" ::: "memory"); }
    else if (t + 2 == nt) { asm volatile("s_waitcnt vmcnt(0)" ::: "memory"); }
    if (t + 1 < nt) {
      __builtin_amdgcn_s_barrier();
      memfence();
    }
  }
#undef STAGE_A
#undef STAGE_B

  // epilogue: C/D layout col=lane&15, row=(lane>>4)*4+r
  float bv[4];
#pragma unroll
  for (int j = 0; j < 4; j++)
    bv[j] = bias ? bias[bn + wn * 64 + j * 16 + lr] : 0.f;
#pragma unroll
  for (int i = 0; i < 8; i++) {
    const int row = bm + wm * 128 + i * 16 + kg * 4;
#pragma unroll
    for (int j = 0; j < 4; j++) {
      const int col = bn + wn * 64 + j * 16 + lr;
#pragma unroll
      for (int r = 0; r < 4; r++)
        C[(size_t)(row + r) * N + col] = acc[i][j][r] + bv[j];
    }
  }
}

// ---------------- depthwise causal conv (D_CONV=4) + silu -------------------
__global__ void k_conv(const float* __restrict__ xz, const float* __restrict__ cw,
                       const float* __restrict__ cb, float* __restrict__ xa) {
  const int bl = blockIdx.x;
  const int l  = bl & (L_SEQ - 1);
  for (int d = threadIdx.x; d < DINNER; d += blockDim.x) {
    float acc = cb[d];
#pragma unroll
    for (int k = 0; k < 4; k++) {
      const int ll = l + k - 3;
      if (ll >= 0)
        acc = fmaf(xz[(size_t)(bl + k - 3) * (2 * DINNER) + d], cw[d * 4 + k], acc);
    }
    xa[(size_t)bl * DINNER + d] = acc / (1.f + __expf(-acc));
  }
}

// ---------------- x_proj: dbl(2048,80) = xa(2048,1536) @ w(1536,80), fp32 ---
__global__ void k_xproj(const float* __restrict__ xa, const float* __restrict__ w,
                        float* __restrict__ dbl) {
  const int t = threadIdx.x;               // 640 = 8 rows x 80 cols
  const int r = blockIdx.x * 8 + t / 80;
  const int c = t % 80;
  const float* xr = xa + (size_t)r * DINNER;
  float acc = 0.f;
  for (int k = 0; k < DINNER; k++) acc = fmaf(xr[k], w[k * 80 + c], acc);
  dbl[(size_t)r * 80 + c] = acc;
}

// ---------------- dt_proj + softplus, fp32 ----------------------------------
__global__ void k_dtproj(const float* __restrict__ dbl, const float* __restrict__ w,
                         const float* __restrict__ bvec, float* __restrict__ dt) {
  const int r = blockIdx.x;
  __shared__ float ds[DTRANK];
  if (threadIdx.x < DTRANK) ds[threadIdx.x] = dbl[(size_t)r * 80 + threadIdx.x];
  __syncthreads();
  for (int c = threadIdx.x; c < DINNER; c += blockDim.x) {
    float acc = bvec[c];
#pragma unroll
    for (int k = 0; k < DTRANK; k++) acc = fmaf(ds[k], w[k * DINNER + c], acc);
    dt[(size_t)r * DINNER + c] = (acc > 20.f) ? acc : log1pf(expf(acc));
  }
}

// ======================= chunk-parallel selective scan =======================
__global__ __launch_bounds__(256) void k_scan1(
    const float* __restrict__ dt, const float* __restrict__ dbl,
    const float* __restrict__ xa, const float* __restrict__ a_log,
    float* __restrict__ P, float* __restrict__ S) {
  const int tid = threadIdx.x;
  const int d = blockIdx.x * 256 + tid;
  const int c = blockIdx.y;
  const int b = blockIdx.z;
  __shared__ float sB[CLEN][DSTATE];
  {
    const int j = tid >> 4, n = tid & 15;
    sB[j][n] = dbl[(size_t)(b * L_SEQ + c * CLEN + j) * 80 + DTRANK + n];
  }
  __syncthreads();
  float a[16];
#pragma unroll
  for (int q = 0; q < 4; q++) {
    const float4 v = *(const float4*)&a_log[d * DSTATE + q * 4];
    a[q*4+0] = -expf(v.x); a[q*4+1] = -expf(v.y);
    a[q*4+2] = -expf(v.z); a[q*4+3] = -expf(v.w);
  }
  float h[16] = {}, p[16];
#pragma unroll
  for (int n = 0; n < 16; n++) p[n] = 1.f;
  const size_t rowb = (size_t)(b * L_SEQ + c * CLEN);
#pragma unroll 4
  for (int j = 0; j < CLEN; j++) {
    const size_t row = rowb + j;
    const float dtv = dt[row * DINNER + d];
    const float xav = xa[row * DINNER + d];
    const float du  = dtv * xav;
#pragma unroll
    for (int n = 0; n < 16; n++) {
      const float dA = __expf(dtv * a[n]);
      h[n] = fmaf(dA, h[n], du * sB[j][n]);
      p[n] *= dA;
    }
  }
  const size_t base = (((size_t)c * B_SZ + b) * DINNER + d) * DSTATE;
#pragma unroll
  for (int q = 0; q < 4; q++) {
    *(float4*)&P[base + q * 4] = make_float4(p[q*4], p[q*4+1], p[q*4+2], p[q*4+3]);
    *(float4*)&S[base + q * 4] = make_float4(h[q*4], h[q*4+1], h[q*4+2], h[q*4+3]);
  }
}

__global__ __launch_bounds__(256) void k_scan2(
    const float* __restrict__ P, const float* __restrict__ S,
    float* __restrict__ Hin) {
  const int gid = blockIdx.x * 256 + threadIdx.x;   // (b*DINNER+d)*16+n
  const int STRIDE = B_SZ * DINNER * DSTATE;        // 49152
  float h = 0.f;
#pragma unroll 4
  for (int c = 0; c < NCH; c++) {
    Hin[(size_t)c * STRIDE + gid] = h;
    h = fmaf(P[(size_t)c * STRIDE + gid], h, S[(size_t)c * STRIDE + gid]);
  }
}

__global__ __launch_bounds__(256) void k_scan3(
    const float* __restrict__ dt, const float* __restrict__ dbl,
    const float* __restrict__ xa, const float* __restrict__ a_log,
    const float* __restrict__ dvec, const float* __restrict__ xz,
    const float* __restrict__ Hin, float* __restrict__ ycmb) {
  const int tid = threadIdx.x;
  const int d = blockIdx.x * 256 + tid;
  const int c = blockIdx.y;
  const int b = blockIdx.z;
  __shared__ float sB[CLEN][DSTATE];
  __shared__ float sC[CLEN][DSTATE];
  {
    const int j = tid >> 4, n = tid & 15;
    const size_t r80 = (size_t)(b * L_SEQ + c * CLEN + j) * 80;
    sB[j][n] = dbl[r80 + DTRANK + n];
    sC[j][n] = dbl[r80 + DTRANK + DSTATE + n];
  }
  __syncthreads();
  float a[16];
#pragma unroll
  for (int q = 0; q < 4; q++) {
    const float4 v = *(const float4*)&a_log[d * DSTATE + q * 4];
    a[q*4+0] = -expf(v.x); a[q*4+1] = -expf(v.y);
    a[q*4+2] = -expf(v.z); a[q*4+3] = -expf(v.w);
  }
  float h[16];
  const size_t base = (((size_t)c * B_SZ + b) * DINNER + d) * DSTATE;
#pragma unroll
  for (int q = 0; q < 4; q++) {
    const float4 v = *(const float4*)&Hin[base + q * 4];
    h[q*4+0] = v.x; h[q*4+1] = v.y; h[q*4+2] = v.z; h[q*4+3] = v.w;
  }
  const float Dv = dvec[d];
  const size_t rowb = (size_t)(b * L_SEQ + c * CLEN);
#pragma unroll 4
  for (int j = 0; j < CLEN; j++) {
    const size_t row = rowb + j;
    const float dtv = dt[row * DINNER + d];
    const float xav = xa[row * DINNER + d];
    const float du  = dtv * xav;
    float y = 0.f;
#pragma unroll
    for (int n = 0; n < 16; n++) {
      const float dA = __expf(dtv * a[n]);
      h[n] = fmaf(dA, h[n], du * sB[j][n]);
      y = fmaf(h[n], sC[j][n], y);
    }
    const float z  = xz[row * (2 * DINNER) + DINNER + d];
    const float sz = z / (1.f + __expf(-z));
    ycmb[row * DINNER + d] = fmaf(xav, Dv, y) * sz;
  }
}

// ============================================================================
extern "C" void kernel_launch(void* const* d_in, const int* in_sizes, int n_in,
                              void* d_out, int out_size, void* d_ws, size_t ws_size,
                              hipStream_t stream) {
  const int*   ids   = (const int*)d_in[0];
  const float* emb   = (const float*)d_in[1];
  const float* w_in  = (const float*)d_in[2];   // 768 x 3072
  const float* cw    = (const float*)d_in[3];   // 1536 x 4
  const float* cb    = (const float*)d_in[4];
  const float* w_x   = (const float*)d_in[5];   // 1536 x 80
  const float* w_dt  = (const float*)d_in[6];   // 48 x 1536
  const float* b_dt  = (const float*)d_in[7];
  const float* a_log = (const float*)d_in[8];   // 1536 x 16
  const float* dvec  = (const float*)d_in[9];
  const float* w_out = (const float*)d_in[10];  // 1536 x 768
  const float* w_lm  = (const float*)d_in[11];  // 768 x 32000
  const float* b_lm  = (const float*)d_in[12];
  float* out = (float*)d_out;

  char* ws = (char*)d_ws;
  size_t off = 0;
  auto alloc = [&](size_t bytes) {
    void* p = ws + off;
    off = (off + bytes + 255) & ~(size_t)255;
    return p;
  };
  float* xw    = (float*)alloc((size_t)BL * DMODEL * 4);
  float* xz    = (float*)alloc((size_t)BL * 2 * DINNER * 4);
  float* xa    = (float*)alloc((size_t)BL * DINNER * 4);
  float* dbl   = (float*)alloc((size_t)BL * 80 * 4);
  float* dt    = (float*)alloc((size_t)BL * DINNER * 4);
  float* ycmb  = (float*)alloc((size_t)BL * DINNER * 4);
  float* yo    = (float*)alloc((size_t)BL * DMODEL * 4);
  bf16* xwh    = (bf16*)alloc((size_t)BL * DMODEL * 2);
  bf16* xwl    = (bf16*)alloc((size_t)BL * DMODEL * 2);
  bf16* wtinh  = (bf16*)alloc((size_t)3072 * DMODEL * 2);
  bf16* wtinl  = (bf16*)alloc((size_t)3072 * DMODEL * 2);
  bf16* ych    = (bf16*)alloc((size_t)BL * DINNER * 2);
  bf16* ycl    = (bf16*)alloc((size_t)BL * DINNER * 2);
  bf16* wtoh   = (bf16*)alloc((size_t)DMODEL * DINNER * 2);
  bf16* wtol   = (bf16*)alloc((size_t)DMODEL * DINNER * 2);
  bf16* yob    = (bf16*)alloc((size_t)BL * DMODEL * 2);
  bf16* wtlm   = (bf16*)alloc((size_t)VOCAB * DMODEL * 2);
  if (off > ws_size) {
    fprintf(stderr, "kernel_launch: ws too small (need %zu, have %zu)\n", off, ws_size);
    return;
  }

  // Scan scratch aliased onto dead-lifetime regions (see round-1 notes)
  float* Pbuf = (float*)xwh;
  float* Sbuf = (float*)ych;
  float* Hin  = (float*)wtlm;

  // allow 128 KiB dynamic LDS for k_gemm8 (capture-safe: no enqueue)
  (void)hipFuncSetAttribute((const void*)k_gemm8,
                            hipFuncAttributeMaxDynamicSharedMemorySize, 131072);

  // 1. embed
  k_embed<<<BL, 192, 0, stream>>>(ids, emb, xw);
  // 2. split activations + transpose-convert in_proj weight
  k_split4<<<(BL * DMODEL / 4 + 255) / 256, 256, 0, stream>>>(xw, xwh, xwl, BL * DMODEL / 4);
  k_tconv<true><<<dim3(3072 / 32, DMODEL / 32), dim3(32, 8), 0, stream>>>(w_in, wtinh, wtinl, DMODEL, 3072);
  // 3. in_proj GEMM (split, fp32-exact-ish): xz = xw @ w_in
  k_gemm<true, false><<<dim3(3072 / 128, BL / 128), 256, 0, stream>>>(
      xwh, xwl, wtinh, wtinl, nullptr, xz, BL, 3072, DMODEL);
  // 4. conv + silu
  k_conv<<<BL, 256, 0, stream>>>(xz, cw, cb, xa);
  // 5. x_proj (fp32)
  k_xproj<<<BL / 8, 640, 0, stream>>>(xa, w_x, dbl);
  // 6. dt_proj + softplus (fp32)
  k_dtproj<<<BL, 256, 0, stream>>>(dbl, w_dt, b_dt, dt);
  // 7. chunk-parallel scan + fused combine epilogue (fp32)
  k_scan1<<<dim3(DINNER / 256, NCH, B_SZ), 256, 0, stream>>>(dt, dbl, xa, a_log, Pbuf, Sbuf);
  k_scan2<<<(B_SZ * DINNER * DSTATE) / 256, 256, 0, stream>>>(Pbuf, Sbuf, Hin);
  k_scan3<<<dim3(DINNER / 256, NCH, B_SZ), 256, 0, stream>>>(dt, dbl, xa, a_log, dvec, xz, Hin, ycmb);
  // 8. out_proj GEMM (split): yo = ycmb @ w_out
  k_split4<<<(BL * DINNER / 4 + 255) / 256, 256, 0, stream>>>(ycmb, ych, ycl, BL * DINNER / 4);
  k_tconv<true><<<dim3(DMODEL / 32, DINNER / 32), dim3(32, 8), 0, stream>>>(w_out, wtoh, wtol, DINNER, DMODEL);
  k_gemm<true, false><<<dim3(DMODEL / 128, BL / 128), 256, 0, stream>>>(
      ych, ycl, wtoh, wtol, nullptr, yo, BL, DMODEL, DINNER);
  // 9. lm_head GEMM: 256x256 8-wave deep-pipelined, bf16 + fp32 bias
  k_cvt4<<<(BL * DMODEL / 4 + 255) / 256, 256, 0, stream>>>(yo, yob, BL * DMODEL / 4);
  k_tconv<false><<<dim3(VOCAB / 32, DMODEL / 32), dim3(32, 8), 0, stream>>>(w_lm, wtlm, nullptr, DMODEL, VOCAB);
  {
    const int mb = BL / 256;                 // 8
    const int nb = VOCAB / 256;              // 125
    k_gemm8<<<mb * nb, 512, 131072, stream>>>(yob, wtlm, b_lm, out,
                                              BL, VOCAB, DMODEL, mb);
  }
}

// Round 6
// 471.551 us; speedup vs baseline: 2.7381x; 1.2090x over previous
//
#include <hip/hip_runtime.h>
#include <hip/hip_bf16.h>
#include <cstdio>
#include <cstdint>

#define B_SZ    2
#define L_SEQ   1024
#define DMODEL  768
#define DINNER  1536
#define DSTATE  16
#define DTRANK  48
#define VOCAB   32000
#define BL      (B_SZ * L_SEQ)   // 2048
#define NCH     64               // scan chunks per sequence
#define CLEN    16               // timesteps per chunk (NCH*CLEN == L_SEQ)

typedef __bf16 bf16;
typedef __bf16 bf16x8 __attribute__((ext_vector_type(8)));
typedef __bf16 bf16x4 __attribute__((ext_vector_type(4)));
typedef float  f32x4  __attribute__((ext_vector_type(4)));

// ---------------- async global->LDS (16B/lane, wave-uniform base + lane*16) --
__device__ __forceinline__ void gload16(const void* g, void* l) {
  __builtin_amdgcn_global_load_lds(
      (const __attribute__((address_space(1))) void*)g,
      (__attribute__((address_space(3))) void*)l, 16, 0, 0);
}
__device__ __forceinline__ void memfence() { asm volatile("" ::: "memory"); }

// ---------------- embedding gather fused with hi/lo bf16 split --------------
__global__ void k_embed(const int* __restrict__ ids, const float* __restrict__ emb,
                        bf16* __restrict__ xh, bf16* __restrict__ xl) {
  const int row = blockIdx.x;
  const int id  = ids[row];
  const float4* s = (const float4*)(emb + (size_t)id * DMODEL);
  const int i = threadIdx.x;             // 192 threads = DMODEL/4
  const float4 v = s[i];
  bf16x4 hv, lv;
  hv[0] = (bf16)v.x; hv[1] = (bf16)v.y; hv[2] = (bf16)v.z; hv[3] = (bf16)v.w;
  lv[0] = (bf16)(v.x - (float)hv[0]); lv[1] = (bf16)(v.y - (float)hv[1]);
  lv[2] = (bf16)(v.z - (float)hv[2]); lv[3] = (bf16)(v.w - (float)hv[3]);
  *(bf16x4*)(xh + (size_t)row * DMODEL + i * 4) = hv;
  *(bf16x4*)(xl + (size_t)row * DMODEL + i * 4) = lv;
}

// ---------------- weight transpose + convert: W(K,N) f32 -> WT(N,K) bf16 ----
template<bool SPLIT>
__global__ void k_tconv(const float* __restrict__ W, bf16* __restrict__ Th,
                        bf16* __restrict__ Tl, int K, int N) {
  __shared__ float t[32][33];
  const int n0 = blockIdx.x * 32;
  const int k0 = blockIdx.y * 32;
  const int tx = threadIdx.x;   // 0..31
  const int ty = threadIdx.y;   // 0..7
#pragma unroll
  for (int i = 0; i < 4; i++)
    t[ty + i * 8][tx] = W[(size_t)(k0 + ty + i * 8) * N + n0 + tx];
  __syncthreads();
#pragma unroll
  for (int i = 0; i < 4; i++) {
    const float v = t[tx][ty + i * 8];
    const bf16 hv = (bf16)v;
    Th[(size_t)(n0 + ty + i * 8) * K + k0 + tx] = hv;
    if constexpr (SPLIT)
      Tl[(size_t)(n0 + ty + i * 8) * K + k0 + tx] = (bf16)(v - (float)hv);
  }
}

// ---------------- bf16 MFMA GEMM, 128x128, double-buffered 2-phase ----------
// stage(t+1) issued BEFORE compute(t); one vmcnt(0)+barrier per K-tile.
// SPLIT: AhBh + AlBh + AhBl. BF16OUT: write C as bf16 (fused cvt).
template<bool SPLIT, bool BIAS, bool BF16OUT>
__global__ __launch_bounds__(256) void k_gemm(
    const bf16* __restrict__ Ah, const bf16* __restrict__ Al,
    const bf16* __restrict__ Bh, const bf16* __restrict__ Bl,
    const float* __restrict__ bias, float* __restrict__ C,
    int M, int N, int K) {
  __shared__ bf16 sAh[2][128 * 32];
  __shared__ bf16 sBh[2][128 * 32];
  __shared__ bf16 sAl[SPLIT ? 2 : 1][SPLIT ? 128 * 32 : 8];
  __shared__ bf16 sBl[SPLIT ? 2 : 1][SPLIT ? 128 * 32 : 8];

  const int tid  = threadIdx.x;
  const int lane = tid & 63;
  const int wave = tid >> 6;
  const int bm = blockIdx.y * 128;
  const int bn = blockIdx.x * 128;

  const int srow = tid >> 2;         // 0..63: staging row
  const int schk = (tid & 3) * 8;    // element offset in 32-wide K slab

  const bf16* gA0 = Ah + (size_t)(bm + srow) * K + schk;
  const bf16* gA1 = gA0 + (size_t)64 * K;
  const bf16* gB0 = Bh + (size_t)(bn + srow) * K + schk;
  const bf16* gB1 = gB0 + (size_t)64 * K;
  const bf16 *gA0l = nullptr, *gA1l = nullptr, *gB0l = nullptr, *gB1l = nullptr;
  if constexpr (SPLIT) {
    gA0l = Al + (size_t)(bm + srow) * K + schk;  gA1l = gA0l + (size_t)64 * K;
    gB0l = Bl + (size_t)(bn + srow) * K + schk;  gB1l = gB0l + (size_t)64 * K;
  }

  const int wm = (wave >> 1) * 64;
  const int wn = (wave & 1) * 64;
  const int lr = lane & 15;
  const int kg = lane >> 4;

  f32x4 acc[4][4] = {};
  const int nt = K >> 5;

#define STG(t_, b_) do {                                                    \
    const size_t ko_ = (size_t)(t_) * 32;                                   \
    gload16(gA0 + ko_, &sAh[b_][tid * 8]);                                  \
    gload16(gA1 + ko_, &sAh[b_][2048 + tid * 8]);                           \
    gload16(gB0 + ko_, &sBh[b_][tid * 8]);                                  \
    gload16(gB1 + ko_, &sBh[b_][2048 + tid * 8]);                           \
    if constexpr (SPLIT) {                                                  \
      gload16(gA0l + ko_, &sAl[b_][tid * 8]);                               \
      gload16(gA1l + ko_, &sAl[b_][2048 + tid * 8]);                        \
      gload16(gB0l + ko_, &sBl[b_][tid * 8]);                               \
      gload16(gB1l + ko_, &sBl[b_][2048 + tid * 8]);                        \
    }                                                                       \
  } while (0)

  STG(0, 0);
  asm volatile("s_waitcnt vmcnt(0)" ::: "memory");
  __builtin_amdgcn_s_barrier();
  memfence();

  for (int t = 0; t < nt; ++t) {
    const int b = t & 1;
    if (t + 1 < nt) STG(t + 1, b ^ 1);   // overlap next-tile staging w/ compute

    bf16x8 af[4], bfv[4];
#pragma unroll
    for (int i = 0; i < 4; i++)
      af[i] = *(const bf16x8*)&sAh[b][(wm + i * 16 + lr) * 32 + kg * 8];
#pragma unroll
    for (int i = 0; i < 4; i++)
      bfv[i] = *(const bf16x8*)&sBh[b][(wn + i * 16 + lr) * 32 + kg * 8];

#pragma unroll
    for (int mi = 0; mi < 4; mi++)
#pragma unroll
      for (int ni = 0; ni < 4; ni++)
        acc[mi][ni] = __builtin_amdgcn_mfma_f32_16x16x32_bf16(
            af[mi], bfv[ni], acc[mi][ni], 0, 0, 0);

    if constexpr (SPLIT) {
      bf16x8 afl[4], bfl[4];
#pragma unroll
      for (int i = 0; i < 4; i++)
        afl[i] = *(const bf16x8*)&sAl[b][(wm + i * 16 + lr) * 32 + kg * 8];
#pragma unroll
      for (int i = 0; i < 4; i++)
        bfl[i] = *(const bf16x8*)&sBl[b][(wn + i * 16 + lr) * 32 + kg * 8];
#pragma unroll
      for (int mi = 0; mi < 4; mi++)
#pragma unroll
        for (int ni = 0; ni < 4; ni++) {
          acc[mi][ni] = __builtin_amdgcn_mfma_f32_16x16x32_bf16(
              afl[mi], bfv[ni], acc[mi][ni], 0, 0, 0);
          acc[mi][ni] = __builtin_amdgcn_mfma_f32_16x16x32_bf16(
              af[mi], bfl[ni], acc[mi][ni], 0, 0, 0);
        }
    }

    asm volatile("s_waitcnt vmcnt(0)" ::: "memory");  // next tile landed
    __builtin_amdgcn_s_barrier();                     // all waves done w/ buf b
    memfence();
  }
#undef STG

#pragma unroll
  for (int mi = 0; mi < 4; mi++) {
#pragma unroll
    for (int ni = 0; ni < 4; ni++) {
      const int col = bn + wn + ni * 16 + lr;
      float bv = 0.f;
      if constexpr (BIAS) bv = bias[col];
#pragma unroll
      for (int r = 0; r < 4; r++) {
        const int row = bm + wm + mi * 16 + kg * 4 + r;
        if constexpr (BF16OUT)
          ((bf16*)C)[(size_t)row * N + col] = (bf16)(acc[mi][ni][r] + bv);
        else
          C[(size_t)row * N + col] = acc[mi][ni][r] + bv;
      }
    }
  }
}

// ========== 128x256 8-wave GEMM, 2-buf / 2 blocks-per-CU =====================
// C(MxN) = A(MxK) * Bt(NxK)^T + bias.  BK=32, 2-deep LDS ring (48 KiB dyn).
// Round-6 theory: acc[8][4] (128 AGPR) capped us at 1 block/CU; wave-tile
// 64x64 (acc 64) + 48 KiB LDS + launch_bounds(512,4) -> 2 blocks/CU, so one
// block's vmcnt(0)-drain overlaps the other block's MFMA (m97/m114 mechanism).
// LDS swizzle unchanged: 16B-slot' = slot ^ ((row>>1)&3); linear gload dest,
// inverse-permuted global source, same XOR on ds_read.
__global__ __launch_bounds__(512, 4) void k_gemm8(
    const bf16* __restrict__ A, const bf16* __restrict__ Bt,
    const float* __restrict__ bias, float* __restrict__ C,
    int M, int N, int K, int mblocks) {
  extern __shared__ bf16 lds[];   // [2 bufs][A 4096 el | B 8192 el]

  // T1: bijective XCD swizzle (gridDim.x % 8 == 0 guaranteed by host)
  const int orig = (blockIdx.x & 7) * ((int)gridDim.x >> 3) + (blockIdx.x >> 3);
  const int bm = (orig % mblocks) * 128;
  const int bn = (orig / mblocks) * 256;

  const int tid  = threadIdx.x;
  const int lane = tid & 63;
  const int wave = tid >> 6;       // 0..7
  const int wm   = wave >> 2;      // 0..1 : M half (64 rows)
  const int wn   = wave & 3;       // 0..3 : N quarter (64 cols)
  const int lr   = lane & 15;
  const int kg   = lane >> 4;      // 0..3 : 16B k-slot
  const int sw   = (lr >> 1) & 3;  // read-side swizzle key

  // staging rows: A wave w -> rows [16w,16w+16); B wave w -> rows [32w,32w+32)
  const int srA = (wave << 4) + (lane >> 2);
  const int srB = (wave << 5) + (lane >> 2);
  const int ssA = (lane & 3) ^ ((srA >> 1) & 3);
  const int ssB = (lane & 3) ^ ((srB >> 1) & 3);   // same key for srB+16
  const size_t gAoff  = (size_t)(bm + srA) * K + ssA * 8;
  const size_t gBoff0 = (size_t)(bn + srB) * K + ssB * 8;
  const size_t gBoff1 = gBoff0 + (size_t)16 * K;

  // fragment read offsets within a buffer (elements, swizzled)
  const int aoff = (wm * 64 + lr) * 32 + ((kg ^ sw) << 3);
  const int boff = (wn * 64 + lr) * 32 + ((kg ^ sw) << 3);

  const int nt = K >> 5;   // 24

#define STAGE(ts_) do {                                                    \
    bf16* lb_ = lds + ((ts_) & 1) * 12288;                                 \
    const size_t ko_ = (size_t)(ts_) * 32;                                 \
    gload16(A  + gAoff  + ko_, lb_ + wave * 512);                          \
    gload16(Bt + gBoff0 + ko_, lb_ + 4096 + wave * 1024);                  \
    gload16(Bt + gBoff1 + ko_, lb_ + 4096 + wave * 1024 + 512);            \
  } while (0)

  f32x4 acc[4][4] = {};

  STAGE(0);
  asm volatile("s_waitcnt vmcnt(0)" ::: "memory");
  __builtin_amdgcn_s_barrier();
  memfence();

  for (int t = 0; t < nt; ++t) {
    if (t + 1 < nt) STAGE(t + 1);   // issue prefetch BEFORE ds_read/MFMA

    const bf16* lA = lds + (t & 1) * 12288;
    const bf16* lB = lA + 4096;

    bf16x8 bfr[4], afr[4];
#pragma unroll
    for (int j = 0; j < 4; j++) bfr[j] = *(const bf16x8*)(lB + boff + j * 512);
#pragma unroll
    for (int i = 0; i < 4; i++) afr[i] = *(const bf16x8*)(lA + aoff + i * 512);

    __builtin_amdgcn_s_setprio(1);
#pragma unroll
    for (int i = 0; i < 4; i++)
#pragma unroll
      for (int j = 0; j < 4; j++)
        acc[i][j] = __builtin_amdgcn_mfma_f32_16x16x32_bf16(afr[i], bfr[j], acc[i][j], 0, 0, 0);
    __builtin_amdgcn_s_setprio(0);

    asm volatile("s_waitcnt vmcnt(0)" ::: "memory");  // tile t+1 landed
    __builtin_amdgcn_s_barrier();
    memfence();
  }
#undef STAGE

  // epilogue: C/D layout col=lane&15, row=(lane>>4)*4+r
  float bv[4];
#pragma unroll
  for (int j = 0; j < 4; j++)
    bv[j] = bias ? bias[bn + wn * 64 + j * 16 + lr] : 0.f;
#pragma unroll
  for (int i = 0; i < 4; i++) {
    const int row = bm + wm * 64 + i * 16 + kg * 4;
#pragma unroll
    for (int j = 0; j < 4; j++) {
      const int col = bn + wn * 64 + j * 16 + lr;
#pragma unroll
      for (int r = 0; r < 4; r++)
        C[(size_t)(row + r) * N + col] = acc[i][j][r] + bv[j];
    }
  }
}

// ---------------- depthwise causal conv (D_CONV=4) + silu -------------------
__global__ void k_conv(const float* __restrict__ xz, const float* __restrict__ cw,
                       const float* __restrict__ cb, float* __restrict__ xa) {
  const int bl = blockIdx.x;
  const int l  = bl & (L_SEQ - 1);
  for (int d = threadIdx.x; d < DINNER; d += blockDim.x) {
    float acc = cb[d];
#pragma unroll
    for (int k = 0; k < 4; k++) {
      const int ll = l + k - 3;
      if (ll >= 0)
        acc = fmaf(xz[(size_t)(bl + k - 3) * (2 * DINNER) + d], cw[d * 4 + k], acc);
    }
    xa[(size_t)bl * DINNER + d] = acc / (1.f + __expf(-acc));
  }
}

// ---------------- x_proj: dbl(2048,80) = xa(2048,1536) @ w(1536,80), fp32 ---
__global__ void k_xproj(const float* __restrict__ xa, const float* __restrict__ w,
                        float* __restrict__ dbl) {
  const int t = threadIdx.x;               // 640 = 8 rows x 80 cols
  const int r = blockIdx.x * 8 + t / 80;
  const int c = t % 80;
  const float* xr = xa + (size_t)r * DINNER;
  float acc = 0.f;
  for (int k = 0; k < DINNER; k++) acc = fmaf(xr[k], w[k * 80 + c], acc);
  dbl[(size_t)r * 80 + c] = acc;
}

// ---------------- dt_proj + softplus, 8 rows/block (w_dt L2 reuse x8) -------
__global__ __launch_bounds__(256) void k_dtproj(
    const float* __restrict__ dbl, const float* __restrict__ w,
    const float* __restrict__ bvec, float* __restrict__ dt) {
  const int r0 = blockIdx.x * 8;
  const int tid = threadIdx.x;
  __shared__ float ds[8][DTRANK];
  for (int i = tid; i < 8 * DTRANK; i += 256)
    ds[i / DTRANK][i % DTRANK] = dbl[(size_t)(r0 + i / DTRANK) * 80 + i % DTRANK];
  __syncthreads();
  for (int c = tid; c < DINNER; c += 256) {
    const float bvc = bvec[c];
    float acc[8];
#pragma unroll
    for (int j = 0; j < 8; j++) acc[j] = bvc;
    for (int k = 0; k < DTRANK; k++) {
      const float wv = w[(size_t)k * DINNER + c];
#pragma unroll
      for (int j = 0; j < 8; j++) acc[j] = fmaf(ds[j][k], wv, acc[j]);
    }
#pragma unroll
    for (int j = 0; j < 8; j++) {
      const float a = acc[j];
      dt[(size_t)(r0 + j) * DINNER + c] = (a > 20.f) ? a : log1pf(expf(a));
    }
  }
}

// ======================= chunk-parallel selective scan =======================
__global__ __launch_bounds__(256) void k_scan1(
    const float* __restrict__ dt, const float* __restrict__ dbl,
    const float* __restrict__ xa, const float* __restrict__ a_log,
    float* __restrict__ P, float* __restrict__ S) {
  const int tid = threadIdx.x;
  const int d = blockIdx.x * 256 + tid;
  const int c = blockIdx.y;
  const int b = blockIdx.z;
  __shared__ float sB[CLEN][DSTATE];
  {
    const int j = tid >> 4, n = tid & 15;
    sB[j][n] = dbl[(size_t)(b * L_SEQ + c * CLEN + j) * 80 + DTRANK + n];
  }
  __syncthreads();
  float a[16];
#pragma unroll
  for (int q = 0; q < 4; q++) {
    const float4 v = *(const float4*)&a_log[d * DSTATE + q * 4];
    a[q*4+0] = -expf(v.x); a[q*4+1] = -expf(v.y);
    a[q*4+2] = -expf(v.z); a[q*4+3] = -expf(v.w);
  }
  float h[16] = {}, p[16];
#pragma unroll
  for (int n = 0; n < 16; n++) p[n] = 1.f;
  const size_t rowb = (size_t)(b * L_SEQ + c * CLEN);
#pragma unroll 4
  for (int j = 0; j < CLEN; j++) {
    const size_t row = rowb + j;
    const float dtv = dt[row * DINNER + d];
    const float xav = xa[row * DINNER + d];
    const float du  = dtv * xav;
#pragma unroll
    for (int n = 0; n < 16; n++) {
      const float dA = __expf(dtv * a[n]);
      h[n] = fmaf(dA, h[n], du * sB[j][n]);
      p[n] *= dA;
    }
  }
  const size_t base = (((size_t)c * B_SZ + b) * DINNER + d) * DSTATE;
#pragma unroll
  for (int q = 0; q < 4; q++) {
    *(float4*)&P[base + q * 4] = make_float4(p[q*4], p[q*4+1], p[q*4+2], p[q*4+3]);
    *(float4*)&S[base + q * 4] = make_float4(h[q*4], h[q*4+1], h[q*4+2], h[q*4+3]);
  }
}

__global__ __launch_bounds__(256) void k_scan2(
    const float* __restrict__ P, const float* __restrict__ S,
    float* __restrict__ Hin) {
  const int gid = blockIdx.x * 256 + threadIdx.x;   // (b*DINNER+d)*16+n
  const int STRIDE = B_SZ * DINNER * DSTATE;        // 49152
  float h = 0.f;
#pragma unroll 4
  for (int c = 0; c < NCH; c++) {
    Hin[(size_t)c * STRIDE + gid] = h;
    h = fmaf(P[(size_t)c * STRIDE + gid], h, S[(size_t)c * STRIDE + gid]);
  }
}

// scan3: re-scan with true h0, fused epilogue, writes hi/lo bf16 split of
// ycmb directly (feeds out_proj A operand; fp32 ycmb buffer eliminated)
__global__ __launch_bounds__(256) void k_scan3(
    const float* __restrict__ dt, const float* __restrict__ dbl,
    const float* __restrict__ xa, const float* __restrict__ a_log,
    const float* __restrict__ dvec, const float* __restrict__ xz,
    const float* __restrict__ Hin, bf16* __restrict__ ych,
    bf16* __restrict__ ycl) {
  const int tid = threadIdx.x;
  const int d = blockIdx.x * 256 + tid;
  const int c = blockIdx.y;
  const int b = blockIdx.z;
  __shared__ float sB[CLEN][DSTATE];
  __shared__ float sC[CLEN][DSTATE];
  {
    const int j = tid >> 4, n = tid & 15;
    const size_t r80 = (size_t)(b * L_SEQ + c * CLEN + j) * 80;
    sB[j][n] = dbl[r80 + DTRANK + n];
    sC[j][n] = dbl[r80 + DTRANK + DSTATE + n];
  }
  __syncthreads();
  float a[16];
#pragma unroll
  for (int q = 0; q < 4; q++) {
    const float4 v = *(const float4*)&a_log[d * DSTATE + q * 4];
    a[q*4+0] = -expf(v.x); a[q*4+1] = -expf(v.y);
    a[q*4+2] = -expf(v.z); a[q*4+3] = -expf(v.w);
  }
  float h[16];
  const size_t base = (((size_t)c * B_SZ + b) * DINNER + d) * DSTATE;
#pragma unroll
  for (int q = 0; q < 4; q++) {
    const float4 v = *(const float4*)&Hin[base + q * 4];
    h[q*4+0] = v.x; h[q*4+1] = v.y; h[q*4+2] = v.z; h[q*4+3] = v.w;
  }
  const float Dv = dvec[d];
  const size_t rowb = (size_t)(b * L_SEQ + c * CLEN);
#pragma unroll 4
  for (int j = 0; j < CLEN; j++) {
    const size_t row = rowb + j;
    const float dtv = dt[row * DINNER + d];
    const float xav = xa[row * DINNER + d];
    const float du  = dtv * xav;
    float y = 0.f;
#pragma unroll
    for (int n = 0; n < 16; n++) {
      const float dA = __expf(dtv * a[n]);
      h[n] = fmaf(dA, h[n], du * sB[j][n]);
      y = fmaf(h[n], sC[j][n], y);
    }
    const float z  = xz[row * (2 * DINNER) + DINNER + d];
    const float sz = z / (1.f + __expf(-z));
    const float val = fmaf(xav, Dv, y) * sz;
    const bf16 hv = (bf16)val;
    ych[row * DINNER + d] = hv;
    ycl[row * DINNER + d] = (bf16)(val - (float)hv);
  }
}

// ============================================================================
extern "C" void kernel_launch(void* const* d_in, const int* in_sizes, int n_in,
                              void* d_out, int out_size, void* d_ws, size_t ws_size,
                              hipStream_t stream) {
  const int*   ids   = (const int*)d_in[0];
  const float* emb   = (const float*)d_in[1];
  const float* w_in  = (const float*)d_in[2];   // 768 x 3072
  const float* cw    = (const float*)d_in[3];   // 1536 x 4
  const float* cb    = (const float*)d_in[4];
  const float* w_x   = (const float*)d_in[5];   // 1536 x 80
  const float* w_dt  = (const float*)d_in[6];   // 48 x 1536
  const float* b_dt  = (const float*)d_in[7];
  const float* a_log = (const float*)d_in[8];   // 1536 x 16
  const float* dvec  = (const float*)d_in[9];
  const float* w_out = (const float*)d_in[10];  // 1536 x 768
  const float* w_lm  = (const float*)d_in[11];  // 768 x 32000
  const float* b_lm  = (const float*)d_in[12];
  float* out = (float*)d_out;

  char* ws = (char*)d_ws;
  size_t off = 0;
  auto alloc = [&](size_t bytes) {
    void* p = ws + off;
    off = (off + bytes + 255) & ~(size_t)255;
    return p;
  };
  float* xw    = (float*)alloc((size_t)BL * DMODEL * 4);   // (unused; layout kept)
  float* xz    = (float*)alloc((size_t)BL * 2 * DINNER * 4);
  float* xa    = (float*)alloc((size_t)BL * DINNER * 4);
  float* dbl   = (float*)alloc((size_t)BL * 80 * 4);
  float* dt    = (float*)alloc((size_t)BL * DINNER * 4);
  float* ycmb  = (float*)alloc((size_t)BL * DINNER * 4);   // (unused; layout kept)
  float* yo    = (float*)alloc((size_t)BL * DMODEL * 4);   // (unused; layout kept)
  bf16* xwh    = (bf16*)alloc((size_t)BL * DMODEL * 2);
  bf16* xwl    = (bf16*)alloc((size_t)BL * DMODEL * 2);
  bf16* wtinh  = (bf16*)alloc((size_t)3072 * DMODEL * 2);
  bf16* wtinl  = (bf16*)alloc((size_t)3072 * DMODEL * 2);
  bf16* ych    = (bf16*)alloc((size_t)BL * DINNER * 2);
  bf16* ycl    = (bf16*)alloc((size_t)BL * DINNER * 2);
  bf16* wtoh   = (bf16*)alloc((size_t)DMODEL * DINNER * 2);
  bf16* wtol   = (bf16*)alloc((size_t)DMODEL * DINNER * 2);
  bf16* yob    = (bf16*)alloc((size_t)BL * DMODEL * 2);
  bf16* wtlm   = (bf16*)alloc((size_t)VOCAB * DMODEL * 2);
  (void)xw; (void)ycmb; (void)yo;
  if (off > ws_size) {
    fprintf(stderr, "kernel_launch: ws too small (need %zu, have %zu)\n", off, ws_size);
    return;
  }

  // Scan scratch aliased onto dead-lifetime regions:
  //  P -> xwh+xwl (dead after in_proj GEMM); S -> ych+ycl (scan3 writes them
  //  AFTER scan2 consumed S); Hin -> wtlm (overwritten by lm tconv after scan3)
  float* Pbuf = (float*)xwh;
  float* Sbuf = (float*)ych;
  float* Hin  = (float*)wtlm;

  (void)hipFuncSetAttribute((const void*)k_gemm8,
                            hipFuncAttributeMaxDynamicSharedMemorySize, 65536);

  // 1. embed fused with hi/lo split
  k_embed<<<BL, DMODEL / 4, 0, stream>>>(ids, emb, xwh, xwl);
  // 2. transpose-convert in_proj weight
  k_tconv<true><<<dim3(3072 / 32, DMODEL / 32), dim3(32, 8), 0, stream>>>(w_in, wtinh, wtinl, DMODEL, 3072);
  // 3. in_proj GEMM (split, fp32-exact-ish): xz = xw @ w_in
  k_gemm<true, false, false><<<dim3(3072 / 128, BL / 128), 256, 0, stream>>>(
      xwh, xwl, wtinh, wtinl, nullptr, xz, BL, 3072, DMODEL);
  // 4. conv + silu
  k_conv<<<BL, 256, 0, stream>>>(xz, cw, cb, xa);
  // 5. x_proj (fp32)
  k_xproj<<<BL / 8, 640, 0, stream>>>(xa, w_x, dbl);
  // 6. dt_proj + softplus (fp32, 8 rows/block)
  k_dtproj<<<BL / 8, 256, 0, stream>>>(dbl, w_dt, b_dt, dt);
  // 7. chunk-parallel scan; scan3 writes split bf16 directly
  k_scan1<<<dim3(DINNER / 256, NCH, B_SZ), 256, 0, stream>>>(dt, dbl, xa, a_log, Pbuf, Sbuf);
  k_scan2<<<(B_SZ * DINNER * DSTATE) / 256, 256, 0, stream>>>(Pbuf, Sbuf, Hin);
  k_scan3<<<dim3(DINNER / 256, NCH, B_SZ), 256, 0, stream>>>(dt, dbl, xa, a_log, dvec, xz, Hin, ych, ycl);
  // 8. out_proj GEMM (split), bf16 output fused (yob)
  k_tconv<true><<<dim3(DMODEL / 32, DINNER / 32), dim3(32, 8), 0, stream>>>(w_out, wtoh, wtol, DINNER, DMODEL);
  k_gemm<true, false, true><<<dim3(DMODEL / 128, BL / 128), 256, 0, stream>>>(
      ych, ycl, wtoh, wtol, nullptr, (float*)yob, BL, DMODEL, DINNER);
  // 9. lm_head GEMM: 128x256 8-wave 2-buf (2 blocks/CU), bf16 + fp32 bias
  k_tconv<false><<<dim3(VOCAB / 32, DMODEL / 32), dim3(32, 8), 0, stream>>>(w_lm, wtlm, nullptr, DMODEL, VOCAB);
  {
    const int mb = BL / 128;                 // 16
    const int nb = VOCAB / 256;              // 125
    k_gemm8<<<mb * nb, 512, 49152, stream>>>(yob, wtlm, b_lm, out,
                                             BL, VOCAB, DMODEL, mb);
  }
}

// Round 7
// 467.416 us; speedup vs baseline: 2.7623x; 1.0088x over previous
//
#include <hip/hip_runtime.h>
#include <hip/hip_bf16.h>
#include <cstdio>
#include <cstdint>

#define B_SZ    2
#define L_SEQ   1024
#define DMODEL  768
#define DINNER  1536
#define DSTATE  16
#define DTRANK  48
#define VOCAB   32000
#define BL      (B_SZ * L_SEQ)   // 2048
#define NCH     64               // scan chunks per sequence
#define CLEN    16               // timesteps per chunk (NCH*CLEN == L_SEQ)

typedef __bf16 bf16;
typedef __bf16 bf16x8 __attribute__((ext_vector_type(8)));
typedef __bf16 bf16x4 __attribute__((ext_vector_type(4)));
typedef float  f32x4  __attribute__((ext_vector_type(4)));

// ---------------- async global->LDS (16B/lane, wave-uniform base + lane*16) --
__device__ __forceinline__ void gload16(const void* g, void* l) {
  __builtin_amdgcn_global_load_lds(
      (const __attribute__((address_space(1))) void*)g,
      (__attribute__((address_space(3))) void*)l, 16, 0, 0);
}
__device__ __forceinline__ void memfence() { asm volatile("" ::: "memory"); }

// ---------------- embedding gather fused with hi/lo bf16 split --------------
__global__ void k_embed(const int* __restrict__ ids, const float* __restrict__ emb,
                        bf16* __restrict__ xh, bf16* __restrict__ xl) {
  const int row = blockIdx.x;
  const int id  = ids[row];
  const float4* s = (const float4*)(emb + (size_t)id * DMODEL);
  const int i = threadIdx.x;             // 192 threads = DMODEL/4
  const float4 v = s[i];
  bf16x4 hv, lv;
  hv[0] = (bf16)v.x; hv[1] = (bf16)v.y; hv[2] = (bf16)v.z; hv[3] = (bf16)v.w;
  lv[0] = (bf16)(v.x - (float)hv[0]); lv[1] = (bf16)(v.y - (float)hv[1]);
  lv[2] = (bf16)(v.z - (float)hv[2]); lv[3] = (bf16)(v.w - (float)hv[3]);
  *(bf16x4*)(xh + (size_t)row * DMODEL + i * 4) = hv;
  *(bf16x4*)(xl + (size_t)row * DMODEL + i * 4) = lv;
}

// ---------------- weight transpose + convert: W(K,N) f32 -> WT(N,K) bf16 ----
template<bool SPLIT>
__global__ void k_tconv(const float* __restrict__ W, bf16* __restrict__ Th,
                        bf16* __restrict__ Tl, int K, int N) {
  __shared__ float t[32][33];
  const int n0 = blockIdx.x * 32;
  const int k0 = blockIdx.y * 32;
  const int tx = threadIdx.x;   // 0..31
  const int ty = threadIdx.y;   // 0..7
#pragma unroll
  for (int i = 0; i < 4; i++)
    t[ty + i * 8][tx] = W[(size_t)(k0 + ty + i * 8) * N + n0 + tx];
  __syncthreads();
#pragma unroll
  for (int i = 0; i < 4; i++) {
    const float v = t[tx][ty + i * 8];
    const bf16 hv = (bf16)v;
    Th[(size_t)(n0 + ty + i * 8) * K + k0 + tx] = hv;
    if constexpr (SPLIT)
      Tl[(size_t)(n0 + ty + i * 8) * K + k0 + tx] = (bf16)(v - (float)hv);
  }
}

// ---------------- bf16 MFMA GEMM, 128x128, double-buffered 2-phase ----------
// stage(t+1) issued BEFORE compute(t); one vmcnt(0)+barrier per K-tile.
// SPLIT: AhBh + AlBh + AhBl. BF16OUT: write C as bf16 (fused cvt).
template<bool SPLIT, bool BIAS, bool BF16OUT>
__global__ __launch_bounds__(256) void k_gemm(
    const bf16* __restrict__ Ah, const bf16* __restrict__ Al,
    const bf16* __restrict__ Bh, const bf16* __restrict__ Bl,
    const float* __restrict__ bias, float* __restrict__ C,
    int M, int N, int K) {
  __shared__ bf16 sAh[2][128 * 32];
  __shared__ bf16 sBh[2][128 * 32];
  __shared__ bf16 sAl[SPLIT ? 2 : 1][SPLIT ? 128 * 32 : 8];
  __shared__ bf16 sBl[SPLIT ? 2 : 1][SPLIT ? 128 * 32 : 8];

  const int tid  = threadIdx.x;
  const int lane = tid & 63;
  const int wave = tid >> 6;
  const int bm = blockIdx.y * 128;
  const int bn = blockIdx.x * 128;

  const int srow = tid >> 2;         // 0..63: staging row
  const int schk = (tid & 3) * 8;    // element offset in 32-wide K slab

  const bf16* gA0 = Ah + (size_t)(bm + srow) * K + schk;
  const bf16* gA1 = gA0 + (size_t)64 * K;
  const bf16* gB0 = Bh + (size_t)(bn + srow) * K + schk;
  const bf16* gB1 = gB0 + (size_t)64 * K;
  const bf16 *gA0l = nullptr, *gA1l = nullptr, *gB0l = nullptr, *gB1l = nullptr;
  if constexpr (SPLIT) {
    gA0l = Al + (size_t)(bm + srow) * K + schk;  gA1l = gA0l + (size_t)64 * K;
    gB0l = Bl + (size_t)(bn + srow) * K + schk;  gB1l = gB0l + (size_t)64 * K;
  }

  const int wm = (wave >> 1) * 64;
  const int wn = (wave & 1) * 64;
  const int lr = lane & 15;
  const int kg = lane >> 4;

  f32x4 acc[4][4] = {};
  const int nt = K >> 5;

#define STG(t_, b_) do {                                                    \
    const size_t ko_ = (size_t)(t_) * 32;                                   \
    gload16(gA0 + ko_, &sAh[b_][tid * 8]);                                  \
    gload16(gA1 + ko_, &sAh[b_][2048 + tid * 8]);                           \
    gload16(gB0 + ko_, &sBh[b_][tid * 8]);                                  \
    gload16(gB1 + ko_, &sBh[b_][2048 + tid * 8]);                           \
    if constexpr (SPLIT) {                                                  \
      gload16(gA0l + ko_, &sAl[b_][tid * 8]);                               \
      gload16(gA1l + ko_, &sAl[b_][2048 + tid * 8]);                        \
      gload16(gB0l + ko_, &sBl[b_][tid * 8]);                               \
      gload16(gB1l + ko_, &sBl[b_][2048 + tid * 8]);                        \
    }                                                                       \
  } while (0)

  STG(0, 0);
  asm volatile("s_waitcnt vmcnt(0)" ::: "memory");
  __builtin_amdgcn_s_barrier();
  memfence();

  for (int t = 0; t < nt; ++t) {
    const int b = t & 1;
    if (t + 1 < nt) STG(t + 1, b ^ 1);   // overlap next-tile staging w/ compute

    bf16x8 af[4], bfv[4];
#pragma unroll
    for (int i = 0; i < 4; i++)
      af[i] = *(const bf16x8*)&sAh[b][(wm + i * 16 + lr) * 32 + kg * 8];
#pragma unroll
    for (int i = 0; i < 4; i++)
      bfv[i] = *(const bf16x8*)&sBh[b][(wn + i * 16 + lr) * 32 + kg * 8];

#pragma unroll
    for (int mi = 0; mi < 4; mi++)
#pragma unroll
      for (int ni = 0; ni < 4; ni++)
        acc[mi][ni] = __builtin_amdgcn_mfma_f32_16x16x32_bf16(
            af[mi], bfv[ni], acc[mi][ni], 0, 0, 0);

    if constexpr (SPLIT) {
      bf16x8 afl[4], bfl[4];
#pragma unroll
      for (int i = 0; i < 4; i++)
        afl[i] = *(const bf16x8*)&sAl[b][(wm + i * 16 + lr) * 32 + kg * 8];
#pragma unroll
      for (int i = 0; i < 4; i++)
        bfl[i] = *(const bf16x8*)&sBl[b][(wn + i * 16 + lr) * 32 + kg * 8];
#pragma unroll
      for (int mi = 0; mi < 4; mi++)
#pragma unroll
        for (int ni = 0; ni < 4; ni++) {
          acc[mi][ni] = __builtin_amdgcn_mfma_f32_16x16x32_bf16(
              afl[mi], bfv[ni], acc[mi][ni], 0, 0, 0);
          acc[mi][ni] = __builtin_amdgcn_mfma_f32_16x16x32_bf16(
              af[mi], bfl[ni], acc[mi][ni], 0, 0, 0);
        }
    }

    asm volatile("s_waitcnt vmcnt(0)" ::: "memory");  // next tile landed
    __builtin_amdgcn_s_barrier();                     // all waves done w/ buf b
    memfence();
  }
#undef STG

#pragma unroll
  for (int mi = 0; mi < 4; mi++) {
#pragma unroll
    for (int ni = 0; ni < 4; ni++) {
      const int col = bn + wn + ni * 16 + lr;
      float bv = 0.f;
      if constexpr (BIAS) bv = bias[col];
#pragma unroll
      for (int r = 0; r < 4; r++) {
        const int row = bm + wm + mi * 16 + kg * 4 + r;
        if constexpr (BF16OUT)
          ((bf16*)C)[(size_t)row * N + col] = (bf16)(acc[mi][ni][r] + bv);
        else
          C[(size_t)row * N + col] = acc[mi][ni][r] + bv;
      }
    }
  }
}

// ========== 128x256 8-wave GEMM, 2-buf / 2 blocks-per-CU =====================
// C(MxN) = A(MxK) * Bt(NxK)^T + bias.  BK=32, 2-deep LDS ring (48 KiB dyn).
// Round-6 theory: acc[8][4] (128 AGPR) capped us at 1 block/CU; wave-tile
// 64x64 (acc 64) + 48 KiB LDS + launch_bounds(512,4) -> 2 blocks/CU, so one
// block's vmcnt(0)-drain overlaps the other block's MFMA (m97/m114 mechanism).
// LDS swizzle unchanged: 16B-slot' = slot ^ ((row>>1)&3); linear gload dest,
// inverse-permuted global source, same XOR on ds_read.
__global__ __launch_bounds__(512, 4) void k_gemm8(
    const bf16* __restrict__ A, const bf16* __restrict__ Bt,
    const float* __restrict__ bias, float* __restrict__ C,
    int M, int N, int K, int mblocks) {
  extern __shared__ bf16 lds[];   // [2 bufs][A 4096 el | B 8192 el]

  // T1: bijective XCD swizzle (gridDim.x % 8 == 0 guaranteed by host)
  const int orig = (blockIdx.x & 7) * ((int)gridDim.x >> 3) + (blockIdx.x >> 3);
  const int bm = (orig % mblocks) * 128;
  const int bn = (orig / mblocks) * 256;

  const int tid  = threadIdx.x;
  const int lane = tid & 63;
  const int wave = tid >> 6;       // 0..7
  const int wm   = wave >> 2;      // 0..1 : M half (64 rows)
  const int wn   = wave & 3;       // 0..3 : N quarter (64 cols)
  const int lr   = lane & 15;
  const int kg   = lane >> 4;      // 0..3 : 16B k-slot
  const int sw   = (lr >> 1) & 3;  // read-side swizzle key

  // staging rows: A wave w -> rows [16w,16w+16); B wave w -> rows [32w,32w+32)
  const int srA = (wave << 4) + (lane >> 2);
  const int srB = (wave << 5) + (lane >> 2);
  const int ssA = (lane & 3) ^ ((srA >> 1) & 3);
  const int ssB = (lane & 3) ^ ((srB >> 1) & 3);   // same key for srB+16
  const size_t gAoff  = (size_t)(bm + srA) * K + ssA * 8;
  const size_t gBoff0 = (size_t)(bn + srB) * K + ssB * 8;
  const size_t gBoff1 = gBoff0 + (size_t)16 * K;

  // fragment read offsets within a buffer (elements, swizzled)
  const int aoff = (wm * 64 + lr) * 32 + ((kg ^ sw) << 3);
  const int boff = (wn * 64 + lr) * 32 + ((kg ^ sw) << 3);

  const int nt = K >> 5;   // 24

#define STAGE(ts_) do {                                                    \
    bf16* lb_ = lds + ((ts_) & 1) * 12288;                                 \
    const size_t ko_ = (size_t)(ts_) * 32;                                 \
    gload16(A  + gAoff  + ko_, lb_ + wave * 512);                          \
    gload16(Bt + gBoff0 + ko_, lb_ + 4096 + wave * 1024);                  \
    gload16(Bt + gBoff1 + ko_, lb_ + 4096 + wave * 1024 + 512);            \
  } while (0)

  f32x4 acc[4][4] = {};

  STAGE(0);
  asm volatile("s_waitcnt vmcnt(0)" ::: "memory");
  __builtin_amdgcn_s_barrier();
  memfence();

  for (int t = 0; t < nt; ++t) {
    if (t + 1 < nt) STAGE(t + 1);   // issue prefetch BEFORE ds_read/MFMA

    const bf16* lA = lds + (t & 1) * 12288;
    const bf16* lB = lA + 4096;

    bf16x8 bfr[4], afr[4];
#pragma unroll
    for (int j = 0; j < 4; j++) bfr[j] = *(const bf16x8*)(lB + boff + j * 512);
#pragma unroll
    for (int i = 0; i < 4; i++) afr[i] = *(const bf16x8*)(lA + aoff + i * 512);

    __builtin_amdgcn_s_setprio(1);
#pragma unroll
    for (int i = 0; i < 4; i++)
#pragma unroll
      for (int j = 0; j < 4; j++)
        acc[i][j] = __builtin_amdgcn_mfma_f32_16x16x32_bf16(afr[i], bfr[j], acc[i][j], 0, 0, 0);
    __builtin_amdgcn_s_setprio(0);

    asm volatile("s_waitcnt vmcnt(0)" ::: "memory");  // tile t+1 landed
    __builtin_amdgcn_s_barrier();
    memfence();
  }
#undef STAGE

  // epilogue: C/D layout col=lane&15, row=(lane>>4)*4+r
  float bv[4];
#pragma unroll
  for (int j = 0; j < 4; j++)
    bv[j] = bias ? bias[bn + wn * 64 + j * 16 + lr] : 0.f;
#pragma unroll
  for (int i = 0; i < 4; i++) {
    const int row = bm + wm * 64 + i * 16 + kg * 4;
#pragma unroll
    for (int j = 0; j < 4; j++) {
      const int col = bn + wn * 64 + j * 16 + lr;
#pragma unroll
      for (int r = 0; r < 4; r++)
        C[(size_t)(row + r) * N + col] = acc[i][j][r] + bv[j];
    }
  }
}

// ---------------- depthwise causal conv (D_CONV=4) + silu -------------------
__global__ void k_conv(const float* __restrict__ xz, const float* __restrict__ cw,
                       const float* __restrict__ cb, float* __restrict__ xa) {
  const int bl = blockIdx.x;
  const int l  = bl & (L_SEQ - 1);
  for (int d = threadIdx.x; d < DINNER; d += blockDim.x) {
    float acc = cb[d];
#pragma unroll
    for (int k = 0; k < 4; k++) {
      const int ll = l + k - 3;
      if (ll >= 0)
        acc = fmaf(xz[(size_t)(bl + k - 3) * (2 * DINNER) + d], cw[d * 4 + k], acc);
    }
    xa[(size_t)bl * DINNER + d] = acc / (1.f + __expf(-acc));
  }
}

// ---------------- x_proj: dbl(2048,80) = xa(2048,1536) @ w(1536,80), fp32 ---
__global__ void k_xproj(const float* __restrict__ xa, const float* __restrict__ w,
                        float* __restrict__ dbl) {
  const int t = threadIdx.x;               // 640 = 8 rows x 80 cols
  const int r = blockIdx.x * 8 + t / 80;
  const int c = t % 80;
  const float* xr = xa + (size_t)r * DINNER;
  float acc = 0.f;
  for (int k = 0; k < DINNER; k++) acc = fmaf(xr[k], w[k * 80 + c], acc);
  dbl[(size_t)r * 80 + c] = acc;
}

// ---------------- dt_proj + softplus, 8 rows/block (w_dt L2 reuse x8) -------
__global__ __launch_bounds__(256) void k_dtproj(
    const float* __restrict__ dbl, const float* __restrict__ w,
    const float* __restrict__ bvec, float* __restrict__ dt) {
  const int r0 = blockIdx.x * 8;
  const int tid = threadIdx.x;
  __shared__ float ds[8][DTRANK];
  for (int i = tid; i < 8 * DTRANK; i += 256)
    ds[i / DTRANK][i % DTRANK] = dbl[(size_t)(r0 + i / DTRANK) * 80 + i % DTRANK];
  __syncthreads();
  for (int c = tid; c < DINNER; c += 256) {
    const float bvc = bvec[c];
    float acc[8];
#pragma unroll
    for (int j = 0; j < 8; j++) acc[j] = bvc;
    for (int k = 0; k < DTRANK; k++) {
      const float wv = w[(size_t)k * DINNER + c];
#pragma unroll
      for (int j = 0; j < 8; j++) acc[j] = fmaf(ds[j][k], wv, acc[j]);
    }
#pragma unroll
    for (int j = 0; j < 8; j++) {
      const float a = acc[j];
      dt[(size_t)(r0 + j) * DINNER + c] = (a > 20.f) ? a : log1pf(expf(a));
    }
  }
}

// ======================= chunk-parallel selective scan =======================
__global__ __launch_bounds__(256) void k_scan1(
    const float* __restrict__ dt, const float* __restrict__ dbl,
    const float* __restrict__ xa, const float* __restrict__ a_log,
    float* __restrict__ P, float* __restrict__ S) {
  const int tid = threadIdx.x;
  const int d = blockIdx.x * 256 + tid;
  const int c = blockIdx.y;
  const int b = blockIdx.z;
  __shared__ float sB[CLEN][DSTATE];
  {
    const int j = tid >> 4, n = tid & 15;
    sB[j][n] = dbl[(size_t)(b * L_SEQ + c * CLEN + j) * 80 + DTRANK + n];
  }
  __syncthreads();
  float a[16];
#pragma unroll
  for (int q = 0; q < 4; q++) {
    const float4 v = *(const float4*)&a_log[d * DSTATE + q * 4];
    a[q*4+0] = -expf(v.x); a[q*4+1] = -expf(v.y);
    a[q*4+2] = -expf(v.z); a[q*4+3] = -expf(v.w);
  }
  float h[16] = {}, p[16];
#pragma unroll
  for (int n = 0; n < 16; n++) p[n] = 1.f;
  const size_t rowb = (size_t)(b * L_SEQ + c * CLEN);
#pragma unroll 4
  for (int j = 0; j < CLEN; j++) {
    const size_t row = rowb + j;
    const float dtv = dt[row * DINNER + d];
    const float xav = xa[row * DINNER + d];
    const float du  = dtv * xav;
#pragma unroll
    for (int n = 0; n < 16; n++) {
      const float dA = __expf(dtv * a[n]);
      h[n] = fmaf(dA, h[n], du * sB[j][n]);
      p[n] *= dA;
    }
  }
  const size_t base = (((size_t)c * B_SZ + b) * DINNER + d) * DSTATE;
#pragma unroll
  for (int q = 0; q < 4; q++) {
    *(float4*)&P[base + q * 4] = make_float4(p[q*4], p[q*4+1], p[q*4+2], p[q*4+3]);
    *(float4*)&S[base + q * 4] = make_float4(h[q*4], h[q*4+1], h[q*4+2], h[q*4+3]);
  }
}

__global__ __launch_bounds__(256) void k_scan2(
    const float* __restrict__ P, const float* __restrict__ S,
    float* __restrict__ Hin) {
  const int gid = blockIdx.x * 256 + threadIdx.x;   // (b*DINNER+d)*16+n
  const int STRIDE = B_SZ * DINNER * DSTATE;        // 49152
  float h = 0.f;
#pragma unroll 4
  for (int c = 0; c < NCH; c++) {
    Hin[(size_t)c * STRIDE + gid] = h;
    h = fmaf(P[(size_t)c * STRIDE + gid], h, S[(size_t)c * STRIDE + gid]);
  }
}

// scan3: re-scan with true h0, fused epilogue, writes hi/lo bf16 split of
// ycmb directly (feeds out_proj A operand; fp32 ycmb buffer eliminated)
__global__ __launch_bounds__(256) void k_scan3(
    const float* __restrict__ dt, const float* __restrict__ dbl,
    const float* __restrict__ xa, const float* __restrict__ a_log,
    const float* __restrict__ dvec, const float* __restrict__ xz,
    const float* __restrict__ Hin, bf16* __restrict__ ych,
    bf16* __restrict__ ycl) {
  const int tid = threadIdx.x;
  const int d = blockIdx.x * 256 + tid;
  const int c = blockIdx.y;
  const int b = blockIdx.z;
  __shared__ float sB[CLEN][DSTATE];
  __shared__ float sC[CLEN][DSTATE];
  {
    const int j = tid >> 4, n = tid & 15;
    const size_t r80 = (size_t)(b * L_SEQ + c * CLEN + j) * 80;
    sB[j][n] = dbl[r80 + DTRANK + n];
    sC[j][n] = dbl[r80 + DTRANK + DSTATE + n];
  }
  __syncthreads();
  float a[16];
#pragma unroll
  for (int q = 0; q < 4; q++) {
    const float4 v = *(const float4*)&a_log[d * DSTATE + q * 4];
    a[q*4+0] = -expf(v.x); a[q*4+1] = -expf(v.y);
    a[q*4+2] = -expf(v.z); a[q*4+3] = -expf(v.w);
  }
  float h[16];
  const size_t base = (((size_t)c * B_SZ + b) * DINNER + d) * DSTATE;
#pragma unroll
  for (int q = 0; q < 4; q++) {
    const float4 v = *(const float4*)&Hin[base + q * 4];
    h[q*4+0] = v.x; h[q*4+1] = v.y; h[q*4+2] = v.z; h[q*4+3] = v.w;
  }
  const float Dv = dvec[d];
  const size_t rowb = (size_t)(b * L_SEQ + c * CLEN);
#pragma unroll 4
  for (int j = 0; j < CLEN; j++) {
    const size_t row = rowb + j;
    const float dtv = dt[row * DINNER + d];
    const float xav = xa[row * DINNER + d];
    const float du  = dtv * xav;
    float y = 0.f;
#pragma unroll
    for (int n = 0; n < 16; n++) {
      const float dA = __expf(dtv * a[n]);
      h[n] = fmaf(dA, h[n], du * sB[j][n]);
      y = fmaf(h[n], sC[j][n], y);
    }
    const float z  = xz[row * (2 * DINNER) + DINNER + d];
    const float sz = z / (1.f + __expf(-z));
    const float val = fmaf(xav, Dv, y) * sz;
    const bf16 hv = (bf16)val;
    ych[row * DINNER + d] = hv;
    ycl[row * DINNER + d] = (bf16)(val - (float)hv);
  }
}

// ============================================================================
extern "C" void kernel_launch(void* const* d_in, const int* in_sizes, int n_in,
                              void* d_out, int out_size, void* d_ws, size_t ws_size,
                              hipStream_t stream) {
  const int*   ids   = (const int*)d_in[0];
  const float* emb   = (const float*)d_in[1];
  const float* w_in  = (const float*)d_in[2];   // 768 x 3072
  const float* cw    = (const float*)d_in[3];   // 1536 x 4
  const float* cb    = (const float*)d_in[4];
  const float* w_x   = (const float*)d_in[5];   // 1536 x 80
  const float* w_dt  = (const float*)d_in[6];   // 48 x 1536
  const float* b_dt  = (const float*)d_in[7];
  const float* a_log = (const float*)d_in[8];   // 1536 x 16
  const float* dvec  = (const float*)d_in[9];
  const float* w_out = (const float*)d_in[10];  // 1536 x 768
  const float* w_lm  = (const float*)d_in[11];  // 768 x 32000
  const float* b_lm  = (const float*)d_in[12];
  float* out = (float*)d_out;

  char* ws = (char*)d_ws;
  size_t off = 0;
  auto alloc = [&](size_t bytes) {
    void* p = ws + off;
    off = (off + bytes + 255) & ~(size_t)255;
    return p;
  };
  float* xw    = (float*)alloc((size_t)BL * DMODEL * 4);   // (unused; layout kept)
  float* xz    = (float*)alloc((size_t)BL * 2 * DINNER * 4);
  float* xa    = (float*)alloc((size_t)BL * DINNER * 4);
  float* dbl   = (float*)alloc((size_t)BL * 80 * 4);
  float* dt    = (float*)alloc((size_t)BL * DINNER * 4);
  float* ycmb  = (float*)alloc((size_t)BL * DINNER * 4);   // (unused; layout kept)
  float* yo    = (float*)alloc((size_t)BL * DMODEL * 4);   // (unused; layout kept)
  bf16* xwh    = (bf16*)alloc((size_t)BL * DMODEL * 2);
  bf16* xwl    = (bf16*)alloc((size_t)BL * DMODEL * 2);
  bf16* wtinh  = (bf16*)alloc((size_t)3072 * DMODEL * 2);
  bf16* wtinl  = (bf16*)alloc((size_t)3072 * DMODEL * 2);
  bf16* ych    = (bf16*)alloc((size_t)BL * DINNER * 2);
  bf16* ycl    = (bf16*)alloc((size_t)BL * DINNER * 2);
  bf16* wtoh   = (bf16*)alloc((size_t)DMODEL * DINNER * 2);
  bf16* wtol   = (bf16*)alloc((size_t)DMODEL * DINNER * 2);
  bf16* yob    = (bf16*)alloc((size_t)BL * DMODEL * 2);
  bf16* wtlm   = (bf16*)alloc((size_t)VOCAB * DMODEL * 2);
  (void)xw; (void)ycmb; (void)yo;
  if (off > ws_size) {
    fprintf(stderr, "kernel_launch: ws too small (need %zu, have %zu)\n", off, ws_size);
    return;
  }

  // Scan scratch aliased onto dead-lifetime regions:
  //  P -> xwh+xwl (dead after in_proj GEMM); S -> ych+ycl (scan3 writes them
  //  AFTER scan2 consumed S); Hin -> wtlm (overwritten by lm tconv after scan3)
  float* Pbuf = (float*)xwh;
  float* Sbuf = (float*)ych;
  float* Hin  = (float*)wtlm;

  (void)hipFuncSetAttribute((const void*)k_gemm8,
                            hipFuncAttributeMaxDynamicSharedMemorySize, 65536);

  // 1. embed fused with hi/lo split
  k_embed<<<BL, DMODEL / 4, 0, stream>>>(ids, emb, xwh, xwl);
  // 2. transpose-convert in_proj weight
  k_tconv<true><<<dim3(3072 / 32, DMODEL / 32), dim3(32, 8), 0, stream>>>(w_in, wtinh, wtinl, DMODEL, 3072);
  // 3. in_proj GEMM (split, fp32-exact-ish): xz = xw @ w_in
  k_gemm<true, false, false><<<dim3(3072 / 128, BL / 128), 256, 0, stream>>>(
      xwh, xwl, wtinh, wtinl, nullptr, xz, BL, 3072, DMODEL);
  // 4. conv + silu
  k_conv<<<BL, 256, 0, stream>>>(xz, cw, cb, xa);
  // 5. x_proj (fp32)
  k_xproj<<<BL / 8, 640, 0, stream>>>(xa, w_x, dbl);
  // 6. dt_proj + softplus (fp32, 8 rows/block)
  k_dtproj<<<BL / 8, 256, 0, stream>>>(dbl, w_dt, b_dt, dt);
  // 7. chunk-parallel scan; scan3 writes split bf16 directly
  k_scan1<<<dim3(DINNER / 256, NCH, B_SZ), 256, 0, stream>>>(dt, dbl, xa, a_log, Pbuf, Sbuf);
  k_scan2<<<(B_SZ * DINNER * DSTATE) / 256, 256, 0, stream>>>(Pbuf, Sbuf, Hin);
  k_scan3<<<dim3(DINNER / 256, NCH, B_SZ), 256, 0, stream>>>(dt, dbl, xa, a_log, dvec, xz, Hin, ych, ycl);
  // 8. out_proj GEMM (split), bf16 output fused (yob)
  k_tconv<true><<<dim3(DMODEL / 32, DINNER / 32), dim3(32, 8), 0, stream>>>(w_out, wtoh, wtol, DINNER, DMODEL);
  k_gemm<true, false, true><<<dim3(DMODEL / 128, BL / 128), 256, 0, stream>>>(
      ych, ycl, wtoh, wtol, nullptr, (float*)yob, BL, DMODEL, DINNER);
  // 9. lm_head GEMM: 128x256 8-wave 2-buf (2 blocks/CU), bf16 + fp32 bias
  k_tconv<false><<<dim3(VOCAB / 32, DMODEL / 32), dim3(32, 8), 0, stream>>>(w_lm, wtlm, nullptr, DMODEL, VOCAB);
  {
    const int mb = BL / 128;                 // 16
    const int nb = VOCAB / 256;              // 125
    k_gemm8<<<mb * nb, 512, 49152, stream>>>(yob, wtlm, b_lm, out,
                                             BL, VOCAB, DMODEL, mb);
  }
}

// Round 8
// 467.099 us; speedup vs baseline: 2.7642x; 1.0007x over previous
//
#include <hip/hip_runtime.h>
#include <hip/hip_bf16.h>
#include <cstdio>
#include <cstdint>

#define B_SZ    2
#define L_SEQ   1024
#define DMODEL  768
#define DINNER  1536
#define DSTATE  16
#define DTRANK  48
#define VOCAB   32000
#define BL      (B_SZ * L_SEQ)   // 2048
#define NCH     64               // scan chunks per sequence
#define CLEN    16               // timesteps per chunk (NCH*CLEN == L_SEQ)

typedef __bf16 bf16;
typedef __bf16 bf16x8 __attribute__((ext_vector_type(8)));
typedef __bf16 bf16x4 __attribute__((ext_vector_type(4)));
typedef float  f32x4  __attribute__((ext_vector_type(4)));

// ---------------- async global->LDS (16B/lane, wave-uniform base + lane*16) --
__device__ __forceinline__ void gload16(const void* g, void* l) {
  __builtin_amdgcn_global_load_lds(
      (const __attribute__((address_space(1))) void*)g,
      (__attribute__((address_space(3))) void*)l, 16, 0, 0);
}
__device__ __forceinline__ void memfence() { asm volatile("" ::: "memory"); }

// ---------------- embedding gather fused with hi/lo bf16 split --------------
__global__ void k_embed(const int* __restrict__ ids, const float* __restrict__ emb,
                        bf16* __restrict__ xh, bf16* __restrict__ xl) {
  const int row = blockIdx.x;
  const int id  = ids[row];
  const float4* s = (const float4*)(emb + (size_t)id * DMODEL);
  const int i = threadIdx.x;             // 192 threads = DMODEL/4
  const float4 v = s[i];
  bf16x4 hv, lv;
  hv[0] = (bf16)v.x; hv[1] = (bf16)v.y; hv[2] = (bf16)v.z; hv[3] = (bf16)v.w;
  lv[0] = (bf16)(v.x - (float)hv[0]); lv[1] = (bf16)(v.y - (float)hv[1]);
  lv[2] = (bf16)(v.z - (float)hv[2]); lv[3] = (bf16)(v.w - (float)hv[3]);
  *(bf16x4*)(xh + (size_t)row * DMODEL + i * 4) = hv;
  *(bf16x4*)(xl + (size_t)row * DMODEL + i * 4) = lv;
}

// ---------------- weight transpose + convert: W(K,N) f32 -> WT(N,K) bf16 ----
template<bool SPLIT>
__global__ void k_tconv(const float* __restrict__ W, bf16* __restrict__ Th,
                        bf16* __restrict__ Tl, int K, int N) {
  __shared__ float t[32][33];
  const int n0 = blockIdx.x * 32;
  const int k0 = blockIdx.y * 32;
  const int tx = threadIdx.x;   // 0..31
  const int ty = threadIdx.y;   // 0..7
#pragma unroll
  for (int i = 0; i < 4; i++)
    t[ty + i * 8][tx] = W[(size_t)(k0 + ty + i * 8) * N + n0 + tx];
  __syncthreads();
#pragma unroll
  for (int i = 0; i < 4; i++) {
    const float v = t[tx][ty + i * 8];
    const bf16 hv = (bf16)v;
    Th[(size_t)(n0 + ty + i * 8) * K + k0 + tx] = hv;
    if constexpr (SPLIT)
      Tl[(size_t)(n0 + ty + i * 8) * K + k0 + tx] = (bf16)(v - (float)hv);
  }
}

// ---------------- bf16 MFMA GEMM, 128x128, double-buffered 2-phase ----------
// stage(t+1) issued BEFORE compute(t); one vmcnt(0)+barrier per K-tile.
// SPLIT: AhBh + AlBh + AhBl. BF16OUT: write C as bf16 (fused cvt).
template<bool SPLIT, bool BIAS, bool BF16OUT>
__global__ __launch_bounds__(256) void k_gemm(
    const bf16* __restrict__ Ah, const bf16* __restrict__ Al,
    const bf16* __restrict__ Bh, const bf16* __restrict__ Bl,
    const float* __restrict__ bias, float* __restrict__ C,
    int M, int N, int K) {
  __shared__ bf16 sAh[2][128 * 32];
  __shared__ bf16 sBh[2][128 * 32];
  __shared__ bf16 sAl[SPLIT ? 2 : 1][SPLIT ? 128 * 32 : 8];
  __shared__ bf16 sBl[SPLIT ? 2 : 1][SPLIT ? 128 * 32 : 8];

  const int tid  = threadIdx.x;
  const int lane = tid & 63;
  const int wave = tid >> 6;
  const int bm = blockIdx.y * 128;
  const int bn = blockIdx.x * 128;

  const int srow = tid >> 2;         // 0..63: staging row
  const int schk = (tid & 3) * 8;    // element offset in 32-wide K slab

  const bf16* gA0 = Ah + (size_t)(bm + srow) * K + schk;
  const bf16* gA1 = gA0 + (size_t)64 * K;
  const bf16* gB0 = Bh + (size_t)(bn + srow) * K + schk;
  const bf16* gB1 = gB0 + (size_t)64 * K;
  const bf16 *gA0l = nullptr, *gA1l = nullptr, *gB0l = nullptr, *gB1l = nullptr;
  if constexpr (SPLIT) {
    gA0l = Al + (size_t)(bm + srow) * K + schk;  gA1l = gA0l + (size_t)64 * K;
    gB0l = Bl + (size_t)(bn + srow) * K + schk;  gB1l = gB0l + (size_t)64 * K;
  }

  const int wm = (wave >> 1) * 64;
  const int wn = (wave & 1) * 64;
  const int lr = lane & 15;
  const int kg = lane >> 4;

  f32x4 acc[4][4] = {};
  const int nt = K >> 5;

#define STG(t_, b_) do {                                                    \
    const size_t ko_ = (size_t)(t_) * 32;                                   \
    gload16(gA0 + ko_, &sAh[b_][tid * 8]);                                  \
    gload16(gA1 + ko_, &sAh[b_][2048 + tid * 8]);                           \
    gload16(gB0 + ko_, &sBh[b_][tid * 8]);                                  \
    gload16(gB1 + ko_, &sBh[b_][2048 + tid * 8]);                           \
    if constexpr (SPLIT) {                                                  \
      gload16(gA0l + ko_, &sAl[b_][tid * 8]);                               \
      gload16(gA1l + ko_, &sAl[b_][2048 + tid * 8]);                        \
      gload16(gB0l + ko_, &sBl[b_][tid * 8]);                               \
      gload16(gB1l + ko_, &sBl[b_][2048 + tid * 8]);                        \
    }                                                                       \
  } while (0)

  STG(0, 0);
  asm volatile("s_waitcnt vmcnt(0)" ::: "memory");
  __builtin_amdgcn_s_barrier();
  memfence();

  for (int t = 0; t < nt; ++t) {
    const int b = t & 1;
    if (t + 1 < nt) STG(t + 1, b ^ 1);   // overlap next-tile staging w/ compute

    bf16x8 af[4], bfv[4];
#pragma unroll
    for (int i = 0; i < 4; i++)
      af[i] = *(const bf16x8*)&sAh[b][(wm + i * 16 + lr) * 32 + kg * 8];
#pragma unroll
    for (int i = 0; i < 4; i++)
      bfv[i] = *(const bf16x8*)&sBh[b][(wn + i * 16 + lr) * 32 + kg * 8];

#pragma unroll
    for (int mi = 0; mi < 4; mi++)
#pragma unroll
      for (int ni = 0; ni < 4; ni++)
        acc[mi][ni] = __builtin_amdgcn_mfma_f32_16x16x32_bf16(
            af[mi], bfv[ni], acc[mi][ni], 0, 0, 0);

    if constexpr (SPLIT) {
      bf16x8 afl[4], bfl[4];
#pragma unroll
      for (int i = 0; i < 4; i++)
        afl[i] = *(const bf16x8*)&sAl[b][(wm + i * 16 + lr) * 32 + kg * 8];
#pragma unroll
      for (int i = 0; i < 4; i++)
        bfl[i] = *(const bf16x8*)&sBl[b][(wn + i * 16 + lr) * 32 + kg * 8];
#pragma unroll
      for (int mi = 0; mi < 4; mi++)
#pragma unroll
        for (int ni = 0; ni < 4; ni++) {
          acc[mi][ni] = __builtin_amdgcn_mfma_f32_16x16x32_bf16(
              afl[mi], bfv[ni], acc[mi][ni], 0, 0, 0);
          acc[mi][ni] = __builtin_amdgcn_mfma_f32_16x16x32_bf16(
              af[mi], bfl[ni], acc[mi][ni], 0, 0, 0);
        }
    }

    asm volatile("s_waitcnt vmcnt(0)" ::: "memory");  // next tile landed
    __builtin_amdgcn_s_barrier();                     // all waves done w/ buf b
    memfence();
  }
#undef STG

#pragma unroll
  for (int mi = 0; mi < 4; mi++) {
#pragma unroll
    for (int ni = 0; ni < 4; ni++) {
      const int col = bn + wn + ni * 16 + lr;
      float bv = 0.f;
      if constexpr (BIAS) bv = bias[col];
#pragma unroll
      for (int r = 0; r < 4; r++) {
        const int row = bm + wm + mi * 16 + kg * 4 + r;
        if constexpr (BF16OUT)
          ((bf16*)C)[(size_t)row * N + col] = (bf16)(acc[mi][ni][r] + bv);
        else
          C[(size_t)row * N + col] = acc[mi][ni][r] + bv;
      }
    }
  }
}

// ========== 128x256 8-wave GEMM, 2-buf / 2 blocks-per-CU =====================
// C(MxN) = A(MxK) * Bt(NxK)^T + bias.  BK=32, 2-deep LDS ring (48 KiB dyn).
// Round-6 theory: acc[8][4] (128 AGPR) capped us at 1 block/CU; wave-tile
// 64x64 (acc 64) + 48 KiB LDS + launch_bounds(512,4) -> 2 blocks/CU, so one
// block's vmcnt(0)-drain overlaps the other block's MFMA (m97/m114 mechanism).
// LDS swizzle unchanged: 16B-slot' = slot ^ ((row>>1)&3); linear gload dest,
// inverse-permuted global source, same XOR on ds_read.
__global__ __launch_bounds__(512, 4) void k_gemm8(
    const bf16* __restrict__ A, const bf16* __restrict__ Bt,
    const float* __restrict__ bias, float* __restrict__ C,
    int M, int N, int K, int mblocks) {
  extern __shared__ bf16 lds[];   // [2 bufs][A 4096 el | B 8192 el]

  // T1: bijective XCD swizzle (gridDim.x % 8 == 0 guaranteed by host)
  const int orig = (blockIdx.x & 7) * ((int)gridDim.x >> 3) + (blockIdx.x >> 3);
  const int bm = (orig % mblocks) * 128;
  const int bn = (orig / mblocks) * 256;

  const int tid  = threadIdx.x;
  const int lane = tid & 63;
  const int wave = tid >> 6;       // 0..7
  const int wm   = wave >> 2;      // 0..1 : M half (64 rows)
  const int wn   = wave & 3;       // 0..3 : N quarter (64 cols)
  const int lr   = lane & 15;
  const int kg   = lane >> 4;      // 0..3 : 16B k-slot
  const int sw   = (lr >> 1) & 3;  // read-side swizzle key

  // staging rows: A wave w -> rows [16w,16w+16); B wave w -> rows [32w,32w+32)
  const int srA = (wave << 4) + (lane >> 2);
  const int srB = (wave << 5) + (lane >> 2);
  const int ssA = (lane & 3) ^ ((srA >> 1) & 3);
  const int ssB = (lane & 3) ^ ((srB >> 1) & 3);   // same key for srB+16
  const size_t gAoff  = (size_t)(bm + srA) * K + ssA * 8;
  const size_t gBoff0 = (size_t)(bn + srB) * K + ssB * 8;
  const size_t gBoff1 = gBoff0 + (size_t)16 * K;

  // fragment read offsets within a buffer (elements, swizzled)
  const int aoff = (wm * 64 + lr) * 32 + ((kg ^ sw) << 3);
  const int boff = (wn * 64 + lr) * 32 + ((kg ^ sw) << 3);

  const int nt = K >> 5;   // 24

#define STAGE(ts_) do {                                                    \
    bf16* lb_ = lds + ((ts_) & 1) * 12288;                                 \
    const size_t ko_ = (size_t)(ts_) * 32;                                 \
    gload16(A  + gAoff  + ko_, lb_ + wave * 512);                          \
    gload16(Bt + gBoff0 + ko_, lb_ + 4096 + wave * 1024);                  \
    gload16(Bt + gBoff1 + ko_, lb_ + 4096 + wave * 1024 + 512);            \
  } while (0)

  f32x4 acc[4][4] = {};

  STAGE(0);
  asm volatile("s_waitcnt vmcnt(0)" ::: "memory");
  __builtin_amdgcn_s_barrier();
  memfence();

  for (int t = 0; t < nt; ++t) {
    if (t + 1 < nt) STAGE(t + 1);   // issue prefetch BEFORE ds_read/MFMA

    const bf16* lA = lds + (t & 1) * 12288;
    const bf16* lB = lA + 4096;

    bf16x8 bfr[4], afr[4];
#pragma unroll
    for (int j = 0; j < 4; j++) bfr[j] = *(const bf16x8*)(lB + boff + j * 512);
#pragma unroll
    for (int i = 0; i < 4; i++) afr[i] = *(const bf16x8*)(lA + aoff + i * 512);

    __builtin_amdgcn_s_setprio(1);
#pragma unroll
    for (int i = 0; i < 4; i++)
#pragma unroll
      for (int j = 0; j < 4; j++)
        acc[i][j] = __builtin_amdgcn_mfma_f32_16x16x32_bf16(afr[i], bfr[j], acc[i][j], 0, 0, 0);
    __builtin_amdgcn_s_setprio(0);

    asm volatile("s_waitcnt vmcnt(0)" ::: "memory");  // tile t+1 landed
    __builtin_amdgcn_s_barrier();
    memfence();
  }
#undef STAGE

  // epilogue: C/D layout col=lane&15, row=(lane>>4)*4+r
  float bv[4];
#pragma unroll
  for (int j = 0; j < 4; j++)
    bv[j] = bias ? bias[bn + wn * 64 + j * 16 + lr] : 0.f;
#pragma unroll
  for (int i = 0; i < 4; i++) {
    const int row = bm + wm * 64 + i * 16 + kg * 4;
#pragma unroll
    for (int j = 0; j < 4; j++) {
      const int col = bn + wn * 64 + j * 16 + lr;
#pragma unroll
      for (int r = 0; r < 4; r++)
        C[(size_t)(row + r) * N + col] = acc[i][j][r] + bv[j];
    }
  }
}

// ---------------- depthwise causal conv (D_CONV=4) + silu -------------------
__global__ void k_conv(const float* __restrict__ xz, const float* __restrict__ cw,
                       const float* __restrict__ cb, float* __restrict__ xa) {
  const int bl = blockIdx.x;
  const int l  = bl & (L_SEQ - 1);
  for (int d = threadIdx.x; d < DINNER; d += blockDim.x) {
    float acc = cb[d];
#pragma unroll
    for (int k = 0; k < 4; k++) {
      const int ll = l + k - 3;
      if (ll >= 0)
        acc = fmaf(xz[(size_t)(bl + k - 3) * (2 * DINNER) + d], cw[d * 4 + k], acc);
    }
    xa[(size_t)bl * DINNER + d] = acc / (1.f + __expf(-acc));
  }
}

// ---------------- x_proj: dbl(2048,80) = xa(2048,1536) @ w(1536,80), fp32 ---
__global__ void k_xproj(const float* __restrict__ xa, const float* __restrict__ w,
                        float* __restrict__ dbl) {
  const int t = threadIdx.x;               // 640 = 8 rows x 80 cols
  const int r = blockIdx.x * 8 + t / 80;
  const int c = t % 80;
  const float* xr = xa + (size_t)r * DINNER;
  float acc = 0.f;
  for (int k = 0; k < DINNER; k++) acc = fmaf(xr[k], w[k * 80 + c], acc);
  dbl[(size_t)r * 80 + c] = acc;
}

// ---------------- dt_proj + softplus, 8 rows/block (w_dt L2 reuse x8) -------
__global__ __launch_bounds__(256) void k_dtproj(
    const float* __restrict__ dbl, const float* __restrict__ w,
    const float* __restrict__ bvec, float* __restrict__ dt) {
  const int r0 = blockIdx.x * 8;
  const int tid = threadIdx.x;
  __shared__ float ds[8][DTRANK];
  for (int i = tid; i < 8 * DTRANK; i += 256)
    ds[i / DTRANK][i % DTRANK] = dbl[(size_t)(r0 + i / DTRANK) * 80 + i % DTRANK];
  __syncthreads();
  for (int c = tid; c < DINNER; c += 256) {
    const float bvc = bvec[c];
    float acc[8];
#pragma unroll
    for (int j = 0; j < 8; j++) acc[j] = bvc;
    for (int k = 0; k < DTRANK; k++) {
      const float wv = w[(size_t)k * DINNER + c];
#pragma unroll
      for (int j = 0; j < 8; j++) acc[j] = fmaf(ds[j][k], wv, acc[j]);
    }
#pragma unroll
    for (int j = 0; j < 8; j++) {
      const float a = acc[j];
      dt[(size_t)(r0 + j) * DINNER + c] = (a > 20.f) ? a : log1pf(expf(a));
    }
  }
}

// ======================= chunk-parallel selective scan =======================
__global__ __launch_bounds__(256) void k_scan1(
    const float* __restrict__ dt, const float* __restrict__ dbl,
    const float* __restrict__ xa, const float* __restrict__ a_log,
    float* __restrict__ P, float* __restrict__ S) {
  const int tid = threadIdx.x;
  const int d = blockIdx.x * 256 + tid;
  const int c = blockIdx.y;
  const int b = blockIdx.z;
  __shared__ float sB[CLEN][DSTATE];
  {
    const int j = tid >> 4, n = tid & 15;
    sB[j][n] = dbl[(size_t)(b * L_SEQ + c * CLEN + j) * 80 + DTRANK + n];
  }
  __syncthreads();
  float a[16];
#pragma unroll
  for (int q = 0; q < 4; q++) {
    const float4 v = *(const float4*)&a_log[d * DSTATE + q * 4];
    a[q*4+0] = -expf(v.x); a[q*4+1] = -expf(v.y);
    a[q*4+2] = -expf(v.z); a[q*4+3] = -expf(v.w);
  }
  float h[16] = {}, p[16];
#pragma unroll
  for (int n = 0; n < 16; n++) p[n] = 1.f;
  const size_t rowb = (size_t)(b * L_SEQ + c * CLEN);
#pragma unroll 4
  for (int j = 0; j < CLEN; j++) {
    const size_t row = rowb + j;
    const float dtv = dt[row * DINNER + d];
    const float xav = xa[row * DINNER + d];
    const float du  = dtv * xav;
#pragma unroll
    for (int n = 0; n < 16; n++) {
      const float dA = __expf(dtv * a[n]);
      h[n] = fmaf(dA, h[n], du * sB[j][n]);
      p[n] *= dA;
    }
  }
  const size_t base = (((size_t)c * B_SZ + b) * DINNER + d) * DSTATE;
#pragma unroll
  for (int q = 0; q < 4; q++) {
    *(float4*)&P[base + q * 4] = make_float4(p[q*4], p[q*4+1], p[q*4+2], p[q*4+3]);
    *(float4*)&S[base + q * 4] = make_float4(h[q*4], h[q*4+1], h[q*4+2], h[q*4+3]);
  }
}

__global__ __launch_bounds__(256) void k_scan2(
    const float* __restrict__ P, const float* __restrict__ S,
    float* __restrict__ Hin) {
  const int gid = blockIdx.x * 256 + threadIdx.x;   // (b*DINNER+d)*16+n
  const int STRIDE = B_SZ * DINNER * DSTATE;        // 49152
  float h = 0.f;
#pragma unroll 4
  for (int c = 0; c < NCH; c++) {
    Hin[(size_t)c * STRIDE + gid] = h;
    h = fmaf(P[(size_t)c * STRIDE + gid], h, S[(size_t)c * STRIDE + gid]);
  }
}

// scan3: re-scan with true h0, fused epilogue, writes hi/lo bf16 split of
// ycmb directly (feeds out_proj A operand; fp32 ycmb buffer eliminated)
__global__ __launch_bounds__(256) void k_scan3(
    const float* __restrict__ dt, const float* __restrict__ dbl,
    const float* __restrict__ xa, const float* __restrict__ a_log,
    const float* __restrict__ dvec, const float* __restrict__ xz,
    const float* __restrict__ Hin, bf16* __restrict__ ych,
    bf16* __restrict__ ycl) {
  const int tid = threadIdx.x;
  const int d = blockIdx.x * 256 + tid;
  const int c = blockIdx.y;
  const int b = blockIdx.z;
  __shared__ float sB[CLEN][DSTATE];
  __shared__ float sC[CLEN][DSTATE];
  {
    const int j = tid >> 4, n = tid & 15;
    const size_t r80 = (size_t)(b * L_SEQ + c * CLEN + j) * 80;
    sB[j][n] = dbl[r80 + DTRANK + n];
    sC[j][n] = dbl[r80 + DTRANK + DSTATE + n];
  }
  __syncthreads();
  float a[16];
#pragma unroll
  for (int q = 0; q < 4; q++) {
    const float4 v = *(const float4*)&a_log[d * DSTATE + q * 4];
    a[q*4+0] = -expf(v.x); a[q*4+1] = -expf(v.y);
    a[q*4+2] = -expf(v.z); a[q*4+3] = -expf(v.w);
  }
  float h[16];
  const size_t base = (((size_t)c * B_SZ + b) * DINNER + d) * DSTATE;
#pragma unroll
  for (int q = 0; q < 4; q++) {
    const float4 v = *(const float4*)&Hin[base + q * 4];
    h[q*4+0] = v.x; h[q*4+1] = v.y; h[q*4+2] = v.z; h[q*4+3] = v.w;
  }
  const float Dv = dvec[d];
  const size_t rowb = (size_t)(b * L_SEQ + c * CLEN);
#pragma unroll 4
  for (int j = 0; j < CLEN; j++) {
    const size_t row = rowb + j;
    const float dtv = dt[row * DINNER + d];
    const float xav = xa[row * DINNER + d];
    const float du  = dtv * xav;
    float y = 0.f;
#pragma unroll
    for (int n = 0; n < 16; n++) {
      const float dA = __expf(dtv * a[n]);
      h[n] = fmaf(dA, h[n], du * sB[j][n]);
      y = fmaf(h[n], sC[j][n], y);
    }
    const float z  = xz[row * (2 * DINNER) + DINNER + d];
    const float sz = z / (1.f + __expf(-z));
    const float val = fmaf(xav, Dv, y) * sz;
    const bf16 hv = (bf16)val;
    ych[row * DINNER + d] = hv;
    ycl[row * DINNER + d] = (bf16)(val - (float)hv);
  }
}

// ============================================================================
extern "C" void kernel_launch(void* const* d_in, const int* in_sizes, int n_in,
                              void* d_out, int out_size, void* d_ws, size_t ws_size,
                              hipStream_t stream) {
  const int*   ids   = (const int*)d_in[0];
  const float* emb   = (const float*)d_in[1];
  const float* w_in  = (const float*)d_in[2];   // 768 x 3072
  const float* cw    = (const float*)d_in[3];   // 1536 x 4
  const float* cb    = (const float*)d_in[4];
  const float* w_x   = (const float*)d_in[5];   // 1536 x 80
  const float* w_dt  = (const float*)d_in[6];   // 48 x 1536
  const float* b_dt  = (const float*)d_in[7];
  const float* a_log = (const float*)d_in[8];   // 1536 x 16
  const float* dvec  = (const float*)d_in[9];
  const float* w_out = (const float*)d_in[10];  // 1536 x 768
  const float* w_lm  = (const float*)d_in[11];  // 768 x 32000
  const float* b_lm  = (const float*)d_in[12];
  float* out = (float*)d_out;

  char* ws = (char*)d_ws;
  size_t off = 0;
  auto alloc = [&](size_t bytes) {
    void* p = ws + off;
    off = (off + bytes + 255) & ~(size_t)255;
    return p;
  };
  float* xw    = (float*)alloc((size_t)BL * DMODEL * 4);   // (unused; layout kept)
  float* xz    = (float*)alloc((size_t)BL * 2 * DINNER * 4);
  float* xa    = (float*)alloc((size_t)BL * DINNER * 4);
  float* dbl   = (float*)alloc((size_t)BL * 80 * 4);
  float* dt    = (float*)alloc((size_t)BL * DINNER * 4);
  float* ycmb  = (float*)alloc((size_t)BL * DINNER * 4);   // (unused; layout kept)
  float* yo    = (float*)alloc((size_t)BL * DMODEL * 4);   // (unused; layout kept)
  bf16* xwh    = (bf16*)alloc((size_t)BL * DMODEL * 2);
  bf16* xwl    = (bf16*)alloc((size_t)BL * DMODEL * 2);
  bf16* wtinh  = (bf16*)alloc((size_t)3072 * DMODEL * 2);
  bf16* wtinl  = (bf16*)alloc((size_t)3072 * DMODEL * 2);
  bf16* ych    = (bf16*)alloc((size_t)BL * DINNER * 2);
  bf16* ycl    = (bf16*)alloc((size_t)BL * DINNER * 2);
  bf16* wtoh   = (bf16*)alloc((size_t)DMODEL * DINNER * 2);
  bf16* wtol   = (bf16*)alloc((size_t)DMODEL * DINNER * 2);
  bf16* yob    = (bf16*)alloc((size_t)BL * DMODEL * 2);
  bf16* wtlm   = (bf16*)alloc((size_t)VOCAB * DMODEL * 2);
  (void)xw; (void)ycmb; (void)yo;
  if (off > ws_size) {
    fprintf(stderr, "kernel_launch: ws too small (need %zu, have %zu)\n", off, ws_size);
    return;
  }

  // Scan scratch aliased onto dead-lifetime regions:
  //  P -> xwh+xwl (dead after in_proj GEMM); S -> ych+ycl (scan3 writes them
  //  AFTER scan2 consumed S); Hin -> wtlm (overwritten by lm tconv after scan3)
  float* Pbuf = (float*)xwh;
  float* Sbuf = (float*)ych;
  float* Hin  = (float*)wtlm;

  (void)hipFuncSetAttribute((const void*)k_gemm8,
                            hipFuncAttributeMaxDynamicSharedMemorySize, 65536);

  // 1. embed fused with hi/lo split
  k_embed<<<BL, DMODEL / 4, 0, stream>>>(ids, emb, xwh, xwl);
  // 2. transpose-convert in_proj weight
  k_tconv<true><<<dim3(3072 / 32, DMODEL / 32), dim3(32, 8), 0, stream>>>(w_in, wtinh, wtinl, DMODEL, 3072);
  // 3. in_proj GEMM (split, fp32-exact-ish): xz = xw @ w_in
  k_gemm<true, false, false><<<dim3(3072 / 128, BL / 128), 256, 0, stream>>>(
      xwh, xwl, wtinh, wtinl, nullptr, xz, BL, 3072, DMODEL);
  // 4. conv + silu
  k_conv<<<BL, 256, 0, stream>>>(xz, cw, cb, xa);
  // 5. x_proj (fp32)
  k_xproj<<<BL / 8, 640, 0, stream>>>(xa, w_x, dbl);
  // 6. dt_proj + softplus (fp32, 8 rows/block)
  k_dtproj<<<BL / 8, 256, 0, stream>>>(dbl, w_dt, b_dt, dt);
  // 7. chunk-parallel scan; scan3 writes split bf16 directly
  k_scan1<<<dim3(DINNER / 256, NCH, B_SZ), 256, 0, stream>>>(dt, dbl, xa, a_log, Pbuf, Sbuf);
  k_scan2<<<(B_SZ * DINNER * DSTATE) / 256, 256, 0, stream>>>(Pbuf, Sbuf, Hin);
  k_scan3<<<dim3(DINNER / 256, NCH, B_SZ), 256, 0, stream>>>(dt, dbl, xa, a_log, dvec, xz, Hin, ych, ycl);
  // 8. out_proj GEMM (split), bf16 output fused (yob)
  k_tconv<true><<<dim3(DMODEL / 32, DINNER / 32), dim3(32, 8), 0, stream>>>(w_out, wtoh, wtol, DINNER, DMODEL);
  k_gemm<true, false, true><<<dim3(DMODEL / 128, BL / 128), 256, 0, stream>>>(
      ych, ycl, wtoh, wtol, nullptr, (float*)yob, BL, DMODEL, DINNER);
  // 9. lm_head GEMM: 128x256 8-wave 2-buf (2 blocks/CU), bf16 + fp32 bias
  k_tconv<false><<<dim3(VOCAB / 32, DMODEL / 32), dim3(32, 8), 0, stream>>>(w_lm, wtlm, nullptr, DMODEL, VOCAB);
  {
    const int mb = BL / 128;                 // 16
    const int nb = VOCAB / 256;              // 125
    k_gemm8<<<mb * nb, 512, 49152, stream>>>(yob, wtlm, b_lm, out,
                                             BL, VOCAB, DMODEL, mb);
  }
}